// Round 4
// baseline (2044.498 us; speedup 1.0000x reference)
//
#include <hip/hip_runtime.h>
#include <math.h>

using frag_ab = __attribute__((ext_vector_type(8))) short;
using f32x4   = __attribute__((ext_vector_type(4))) float;

__device__ __forceinline__ unsigned short f2b(float f) {
    unsigned u = __float_as_uint(f);
    u += 0x7fffu + ((u >> 16) & 1u);       // RNE
    return (unsigned short)(u >> 16);
}
__device__ __forceinline__ void bf8_to_f(uint4 v, float* f) {
    const unsigned* p = (const unsigned*)&v;
    #pragma unroll
    for (int q = 0; q < 4; ++q) {
        unsigned u = p[q];
        f[2*q]   = __uint_as_float(u << 16);
        f[2*q+1] = __uint_as_float(u & 0xffff0000u);
    }
}

// ---------------- weight transforms: out[tap][co][ci] bf16 ------------------
// generic (small tensors only)
__global__ void k_wt(const float* __restrict__ in, unsigned short* __restrict__ out,
                     int total, int CO, int CI, int sO, int sI) {
    int i = blockIdx.x * 256 + threadIdx.x;
    if (i >= total) return;
    int ci = i % CI;
    int r  = i / CI;
    int co = r % CO;
    int tp = r / CO;
    out[i] = f2b(in[(size_t)co * sO + (size_t)ci * sI + tp]);
}
// 16-tap 256x256 (conv2 / convT1), CO=CI=256
__global__ void k_wt16(const float* __restrict__ in, unsigned short* __restrict__ out,
                       int sO, int sI) {
    int i = blockIdx.x * 256 + threadIdx.x;      // < 16*65536
    int ci = i & 255, r = i >> 8;
    int co = r & 255, tp = r >> 8;
    out[i] = f2b(in[(size_t)co * sO + (size_t)ci * sI + tp]);
}
// 4x fused 3x3 256x256
__global__ void k_wt3(const float* p0, const float* p1, const float* p2, const float* p3,
                      unsigned short* o0, unsigned short* o1, unsigned short* o2,
                      unsigned short* o3) {
    int z = blockIdx.y;
    const float* in = (z == 0) ? p0 : (z == 1) ? p1 : (z == 2) ? p2 : p3;
    unsigned short* out = (z == 0) ? o0 : (z == 1) ? o1 : (z == 2) ? o2 : o3;
    int i = blockIdx.x * 256 + threadIdx.x;      // < 9*65536 (=589824, exact)
    int ci = i & 255, r = i >> 8;
    int co = r & 255, tp = r >> 8;
    out[i] = f2b(in[(size_t)co * 2304 + (size_t)ci * 9 + tp]);
}
// 4x fused 1x1 256x256
__global__ void k_wt1(const float* p0, const float* p1, const float* p2, const float* p3,
                      unsigned short* o0, unsigned short* o1, unsigned short* o2,
                      unsigned short* o3) {
    int z = blockIdx.y;
    const float* in = (z == 0) ? p0 : (z == 1) ? p1 : (z == 2) ? p2 : p3;
    unsigned short* out = (z == 0) ? o0 : (z == 1) ? o1 : (z == 2) ? o2 : o3;
    int i = blockIdx.x * 256 + threadIdx.x;      // < 65536
    int ci = i & 255, co = i >> 8;
    out[i] = f2b(in[co * 256 + ci]);
}

// e2[k] = sum_d emb[k][d]^2
__global__ void k_e2(const float* __restrict__ emb, float* __restrict__ e2) {
    int k = blockIdx.x * 256 + threadIdx.x;
    if (k < 512) {
        const float* r = emb + k * 256;
        float s = 0.f;
        #pragma unroll 8
        for (int d = 0; d < 256; ++d) s += r[d] * r[d];
        e2[k] = s;
    }
}

// ---------------- conv1: 4x4 s2 p1, 3->256, 128->64, relu, NHWC bf16 out ----
__global__ __launch_bounds__(256) void k_conv1(const float* __restrict__ x,
        const float* __restrict__ w, const float* __restrict__ bias,
        unsigned short* __restrict__ out) {
    int t = threadIdx.x;
    int y = blockIdx.x * 4 + (t >> 6);
    int xq = t & 63;
    int b = blockIdx.y;
    float patch[48];
    #pragma unroll
    for (int ci = 0; ci < 3; ++ci)
        #pragma unroll
        for (int ky = 0; ky < 4; ++ky)
            #pragma unroll
            for (int kx = 0; kx < 4; ++kx) {
                int sy = 2*y - 1 + ky, sx = 2*xq - 1 + kx;
                float v = 0.f;
                if ((unsigned)sy < 128u && (unsigned)sx < 128u)
                    v = x[((b*3 + ci)*128 + sy)*128 + sx];
                patch[(ci*4 + ky)*4 + kx] = v;
            }
    unsigned short* op = out + (((size_t)(b*64 + y)*64 + xq) << 8);
    for (int c8 = 0; c8 < 32; ++c8) {
        unsigned short u8[8];
        #pragma unroll
        for (int cc = 0; cc < 8; ++cc) {
            int co = c8*8 + cc;
            float a = bias[co];
            #pragma unroll
            for (int k = 0; k < 48; ++k) a = fmaf(w[co*48 + k], patch[k], a);
            u8[cc] = f2b(fmaxf(a, 0.f));
        }
        *(uint4*)(op + c8*8) = *(uint4*)u8;
    }
}

// ---------------- unified implicit-GEMM conv (bf16 MFMA) --------------------
// block 256 = 4 waves; tile M=128 px x N=128 co; K staged in 128-ci chunks.
// wave: 64px x 64co quadrant, 4x4 16x16 fragments, 64 MFMA per barrier pair.
template<int MODE, bool RELU_OUT>
__global__ __launch_bounds__(256) void k_cgemm(
        const unsigned short* __restrict__ A,   // bf16 NHWC [B][Hin][Win][256]
        const unsigned short* __restrict__ Wt,  // bf16 [T][256co][256ci]
        const float* __restrict__ bias,
        const float* __restrict__ skipF,        // fp32 NHWC (nullable)
        unsigned short* __restrict__ outB,      // bf16 NHWC (nullable)
        float* __restrict__ outFn,              // fp32 NHWC (nullable)
        float* __restrict__ outFc) {            // fp32 NCHW 32x32 (nullable)
    constexpr int NTAPS = (MODE==0) ? 16 : (MODE==1) ? 9 : (MODE==2) ? 1 : 4;
    constexpr int HIN   = (MODE==0) ? 64 : 32;
    constexpr bool RELU_A = (MODE==1);
    constexpr bool ISCT   = (MODE==3);

    __shared__ __align__(16) unsigned short As[128*128];  // 32 KB, row=px, 256B/row
    __shared__ __align__(16) unsigned short Bs[128*128];  // 32 KB, row=co

    int t = threadIdx.x;
    int cob = blockIdx.x;            // 0..1 : co block of 128
    int y0  = blockIdx.y * 4;        // 4 out-rows in 32-grid
    int bz  = blockIdx.z;
    int b   = ISCT ? (bz >> 2) : bz;
    int par = ISCT ? (bz & 3) : 0;
    int psy = par >> 1, psx = par & 1;

    // staging: thread covers chunk scc (16B) of rows sr0+16q, q=0..7
    int scc = t & 15, sr0 = t >> 4;

    // mfma lane coords
    int wv = t >> 6, lane = t & 63;
    int mq = (wv >> 1) * 64, nq = (wv & 1) * 64;
    int lg = lane >> 4, lr = lane & 15;

    f32x4 acc[4][4];
    #pragma unroll
    for (int i = 0; i < 4; ++i)
        #pragma unroll
        for (int j = 0; j < 4; ++j) acc[i][j] = (f32x4){0.f,0.f,0.f,0.f};

    for (int tap = 0; tap < NTAPS; ++tap) {
        int tdy, tdx, wtap;
        if (MODE == 0)      { tdy = tap >> 2; tdx = tap & 3; wtap = tap; }
        else if (MODE == 1) { tdy = tap / 3;  tdx = tap % 3; wtap = tap; }
        else if (MODE == 2) { tdy = 0; tdx = 0; wtap = 0; }
        else { int jy = tap >> 1, jx = tap & 1;
               tdy = psy - jy; tdx = psx - jx;
               wtap = ((psy ? 0 : 1) + 2*jy) * 4 + ((psx ? 0 : 1) + 2*jx); }
        const unsigned short* wb = Wt + ((size_t)wtap << 16) + ((size_t)cob << 15);

        for (int half = 0; half < 2; ++half) {
            int kk0 = half * 128;
            __syncthreads();
            #pragma unroll
            for (int q = 0; q < 8; ++q) {
                int row = sr0 + 16*q;
                int soy = y0 + (row >> 5), sox = row & 31;
                int sy = (MODE == 0) ? (2*soy - 1 + tdy)
                       : (MODE == 1) ? (soy - 1 + tdy) : (soy + tdy);
                int sx = (MODE == 0) ? (2*sox - 1 + tdx)
                       : (MODE == 1) ? (sox - 1 + tdx) : (sox + tdx);
                bool val = ((unsigned)sy < (unsigned)HIN) && ((unsigned)sx < (unsigned)HIN);
                uint4 av = {0,0,0,0};
                if (val)
                    av = *(const uint4*)(A + ((((size_t)(b*HIN + sy))*HIN + sx) << 8)
                                           + kk0 + scc*8);
                if (RELU_A) {
                    unsigned* p = (unsigned*)&av;
                    #pragma unroll
                    for (int qq = 0; qq < 4; ++qq) {
                        unsigned s = p[qq] & 0x80008000u;
                        p[qq] &= ~((s >> 15) * 0xFFFFu);
                    }
                }
                *(uint4*)((char*)As + row*256 + ((scc ^ (row & 7)) << 4)) = av;
                uint4 bv = *(const uint4*)(wb + (((size_t)row) << 8) + kk0 + scc*8);
                *(uint4*)((char*)Bs + row*256 + ((scc ^ (row & 7)) << 4)) = bv;
            }
            __syncthreads();
            #pragma unroll
            for (int ks = 0; ks < 4; ++ks) {
                int c = ks*4 + lg;
                frag_ab af[4], bf[4];
                #pragma unroll
                for (int i = 0; i < 4; ++i) {
                    int ar = mq + i*16 + lr;
                    af[i] = *(const frag_ab*)((const char*)As + ar*256 + ((c ^ (ar & 7)) << 4));
                    int br = nq + i*16 + lr;
                    bf[i] = *(const frag_ab*)((const char*)Bs + br*256 + ((c ^ (br & 7)) << 4));
                }
                #pragma unroll
                for (int i = 0; i < 4; ++i)
                    #pragma unroll
                    for (int j = 0; j < 4; ++j)
                        acc[i][j] = __builtin_amdgcn_mfma_f32_16x16x32_bf16(
                                        af[i], bf[j], acc[i][j], 0, 0, 0);
            }
        }
    }

    // epilogue
    #pragma unroll
    for (int mf = 0; mf < 4; ++mf) {
        #pragma unroll
        for (int nf = 0; nf < 4; ++nf) {
            int co = cob*128 + nq + nf*16 + lr;
            float bb = bias[co];
            f32x4 v = acc[mf][nf];
            #pragma unroll
            for (int j = 0; j < 4; ++j) {
                int prow = mq + mf*16 + lg*4 + j;
                int oy = y0 + (prow >> 5);
                int ox = prow & 31;
                size_t pix;
                if (ISCT) pix = ((size_t)(b*64 + (2*oy + psy)))*64 + (2*ox + psx);
                else      pix = ((size_t)(b*32 + oy))*32 + ox;
                float xv = v[j] + bb;
                if (skipF) xv += skipF[pix*256 + co];
                if (RELU_OUT) xv = fmaxf(xv, 0.f);
                if (outB)  outB[pix*256 + co] = f2b(xv);
                if (outFn) outFn[pix*256 + co] = xv;
                if (outFc) outFc[(((size_t)b*256 + co) << 10) + oy*32 + ox] = xv;
            }
        }
    }
}

// ---------------- VQ: lat = argmin_k(e2[k] - 2*dot(z, emb_k)), fp32 ---------
// block 256 = 64 k-groups x 4 pos-groups; 16 positions per block; grid (64,32)
__global__ __launch_bounds__(256) void k_vq(const float* __restrict__ ze,
        const float* __restrict__ emb, const float* __restrict__ e2,
        int* __restrict__ lat) {
    __shared__ __align__(16) float zt[256 * 16];   // [d][pos] 16 KB
    __shared__ float sv[256 * 4];
    __shared__ int   si[256 * 4];
    int t = threadIdx.x;
    int y = blockIdx.x >> 1, xh = (blockIdx.x & 1) * 16;
    int b = blockIdx.y;
    const float* zp = ze + (size_t)(b * 256) * 1024 + y * 32 + xh;
    #pragma unroll
    for (int i = 0; i < 16; ++i) {
        int l = i * 256 + t;                  // 0..4095 = d*16 + xx
        zt[l] = zp[(l >> 4) * 1024 + (l & 15)];
    }
    __syncthreads();
    int kg = t & 63, pg = t >> 6;
    int k0 = kg * 8;
    const float* ep = emb + (size_t)k0 * 256;
    float acc[4][8];
    #pragma unroll
    for (int p = 0; p < 4; ++p)
        #pragma unroll
        for (int j = 0; j < 8; ++j) acc[p][j] = 0.f;
    for (int d = 0; d < 256; d += 4) {
        float4 ev[8];
        #pragma unroll
        for (int j = 0; j < 8; ++j) ev[j] = *(const float4*)(ep + j*256 + d);
        #pragma unroll
        for (int dd = 0; dd < 4; ++dd) {
            float4 zv = *(const float4*)&zt[(d + dd) * 16 + pg * 4];
            #pragma unroll
            for (int j = 0; j < 8; ++j) {
                float e = ((const float*)&ev[j])[dd];
                acc[0][j] = fmaf(e, zv.x, acc[0][j]);
                acc[1][j] = fmaf(e, zv.y, acc[1][j]);
                acc[2][j] = fmaf(e, zv.z, acc[2][j]);
                acc[3][j] = fmaf(e, zv.w, acc[3][j]);
            }
        }
    }
    float minv[4] = {1e30f, 1e30f, 1e30f, 1e30f};
    int   mink[4] = {0, 0, 0, 0};
    #pragma unroll
    for (int j = 0; j < 8; ++j) {
        float ee = e2[k0 + j];
        #pragma unroll
        for (int p = 0; p < 4; ++p) {
            float dist = ee - 2.f * acc[p][j];
            if (dist < minv[p]) { minv[p] = dist; mink[p] = k0 + j; }
        }
    }
    #pragma unroll
    for (int p = 0; p < 4; ++p) { sv[t*4 + p] = minv[p]; si[t*4 + p] = mink[p]; }
    __syncthreads();
    if (t < 16) {
        int pg2 = t >> 2, jj = t & 3;
        float bv = 1e30f; int bk = 0x7fffffff;
        for (int m = 0; m < 64; ++m) {
            int idx = (pg2 * 64 + m) * 4 + jj;
            float v = sv[idx]; int k = si[idx];
            if (v < bv || (v == bv && k < bk)) { bv = v; bk = k; }
        }
        lat[(b * 32 + y) * 32 + xh + t] = bk;
    }
}

// gather: zq NCHW fp32 (d_out) + NHWC bf16 + NHWC fp32
__global__ __launch_bounds__(256) void k_gather(const int* __restrict__ lat,
        const float* __restrict__ emb, float* __restrict__ zqc,
        unsigned short* __restrict__ zqB, float* __restrict__ zqF) {
    __shared__ int ll[32];
    int t = threadIdx.x, y = blockIdx.x, b = blockIdx.y;
    if (t < 32) ll[t] = lat[(b * 32 + y) * 32 + t];
    __syncthreads();
    #pragma unroll
    for (int i = 0; i < 32; ++i) {
        int l = i * 256 + t;
        int d = l >> 5, xx = l & 31;
        zqc[(((size_t)b*256 + d) << 10) + y*32 + xx] = emb[ll[xx]*256 + d];
    }
    int xx = t & 31, dg = t >> 5;
    const float* e = emb + ll[xx]*256 + dg*32;
    size_t off = ((((size_t)(b*32 + y)*32 + xx)) << 8) + dg*32;
    #pragma unroll
    for (int q = 0; q < 8; ++q) {
        float4 v = *(const float4*)(e + q*4);
        *(float4*)(zqF + off + q*4) = v;
        uint2 pk;
        pk.x = (unsigned)f2b(v.x) | ((unsigned)f2b(v.y) << 16);
        pk.y = (unsigned)f2b(v.z) | ((unsigned)f2b(v.w) << 16);
        *(uint2*)(zqB + off + q*4) = pk;
    }
}

// ---------------- convT2: 4x4 s2 p1, 256->3, 64->128, sigmoid, NCHW fp32 ----
__global__ __launch_bounds__(256) void k_convt2(const unsigned short* __restrict__ in,
        const unsigned short* __restrict__ Wt,  // [16][3][256] bf16
        const float* __restrict__ bias, float* __restrict__ out) {
    __shared__ __align__(16) unsigned short slab[4*66*32];
    __shared__ __align__(16) unsigned short wl[16*3*32];
    int t = threadIdx.x;
    int b = blockIdx.y;
    int oy0 = blockIdx.x * 4;
    int u0 = oy0 >> 1;
    int oyl = t >> 7, ox = t & 127;
    int sy = oyl & 1, sx = ox & 1;
    int v = ox >> 1;
    float acc0[3] = {0.f,0.f,0.f}, acc1[3] = {0.f,0.f,0.f};
    for (int kc = 0; kc < 8; ++kc) {
        __syncthreads();
        for (int i = t; i < 4*66*4; i += 256) {
            int g = i & 3; int cidx = i >> 2;
            int cc = cidx % 66, ri = cidx / 66;
            int iy = u0 - 1 + ri, ix = cc - 1;
            uint4 v4 = {0,0,0,0};
            if ((unsigned)iy < 64u && (unsigned)ix < 64u)
                v4 = *(const uint4*)(in + (((size_t)(b*64 + iy)*64 + ix) << 8)
                                        + kc*32 + g*8);
            *(uint4*)(&slab[(ri*66 + cc)*32 + g*8]) = v4;
        }
        for (int i = t; i < 1536; i += 256)
            wl[i] = Wt[(i >> 5) * 256 + kc*32 + (i & 31)];
        __syncthreads();
        #pragma unroll
        for (int jy = 0; jy < 2; ++jy) {
            int duy = sy - jy;
            int riA = 1 + duy;
            #pragma unroll
            for (int jx = 0; jx < 2; ++jx) {
                int dvx = sx - jx;
                int cc = v + dvx + 1;
                int wtap = ((sy ? 0 : 1) + 2*jy)*4 + ((sx ? 0 : 1) + 2*jx);
                const unsigned short* sA = &slab[(riA*66 + cc)*32];
                const unsigned short* sB = sA + 66*32;
                const unsigned short* wp = &wl[wtap*96];
                #pragma unroll
                for (int c8 = 0; c8 < 4; ++c8) {
                    float fA[8], fB[8], w0[8], w1[8], w2[8];
                    bf8_to_f(*(const uint4*)(sA + c8*8), fA);
                    bf8_to_f(*(const uint4*)(sB + c8*8), fB);
                    bf8_to_f(*(const uint4*)(wp + c8*8), w0);
                    bf8_to_f(*(const uint4*)(wp + 32 + c8*8), w1);
                    bf8_to_f(*(const uint4*)(wp + 64 + c8*8), w2);
                    #pragma unroll
                    for (int q = 0; q < 8; ++q) {
                        acc0[0] = fmaf(fA[q], w0[q], acc0[0]);
                        acc0[1] = fmaf(fA[q], w1[q], acc0[1]);
                        acc0[2] = fmaf(fA[q], w2[q], acc0[2]);
                        acc1[0] = fmaf(fB[q], w0[q], acc1[0]);
                        acc1[1] = fmaf(fB[q], w1[q], acc1[1]);
                        acc1[2] = fmaf(fB[q], w2[q], acc1[2]);
                    }
                }
            }
        }
    }
    #pragma unroll
    for (int co = 0; co < 3; ++co) {
        float b0 = acc0[co] + bias[co];
        float b1 = acc1[co] + bias[co];
        out[(((size_t)b*3 + co) << 14) + (oy0 + oyl)*128 + ox]     = 1.f/(1.f + __expf(-b0));
        out[(((size_t)b*3 + co) << 14) + (oy0 + oyl + 2)*128 + ox] = 1.f/(1.f + __expf(-b1));
    }
}

extern "C" void kernel_launch(void* const* d_in, const int* in_sizes, int n_in,
                              void* d_out, int out_size, void* d_ws, size_t ws_size,
                              hipStream_t stream) {
    const float* x     = (const float*)d_in[0];
    const float* ec1w  = (const float*)d_in[1];
    const float* ec1b  = (const float*)d_in[2];
    const float* ec2w  = (const float*)d_in[3];
    const float* ec2b  = (const float*)d_in[4];
    const float* er1w1 = (const float*)d_in[5];
    const float* er1b1 = (const float*)d_in[6];
    const float* er1w2 = (const float*)d_in[7];
    const float* er1b2 = (const float*)d_in[8];
    const float* er2w1 = (const float*)d_in[9];
    const float* er2b1 = (const float*)d_in[10];
    const float* er2w2 = (const float*)d_in[11];
    const float* er2b2 = (const float*)d_in[12];
    const float* emb   = (const float*)d_in[13];
    const float* dr1w1 = (const float*)d_in[14];
    const float* dr1b1 = (const float*)d_in[15];
    const float* dr1w2 = (const float*)d_in[16];
    const float* dr1b2 = (const float*)d_in[17];
    const float* dr2w1 = (const float*)d_in[18];
    const float* dr2b1 = (const float*)d_in[19];
    const float* dr2w2 = (const float*)d_in[20];
    const float* dr2b2 = (const float*)d_in[21];
    const float* dt1w  = (const float*)d_in[22];
    const float* dt1b  = (const float*)d_in[23];
    const float* dt2w  = (const float*)d_in[24];
    const float* dt2b  = (const float*)d_in[25];

    float* outp = (float*)d_out;
    float* xt = outp;                    // x_tilde 1,572,864
    float* ze = outp + 1572864;          // z_e_x   8,388,608
    float* zq = ze + 8388608;            // z_q_x   8,388,608

    char* ws = (char*)d_ws;
    unsigned short* h1B  = (unsigned short*)(ws);                 // 67,108,864 B
    unsigned short* B0   = (unsigned short*)(ws + 67108864);      // 16,777,216
    unsigned short* B1   = (unsigned short*)(ws + 83886080);      // 16,777,216
    unsigned short* T3   = (unsigned short*)(ws + 100663296);     // 16,777,216
    float*          F0   = (float*)(ws + 117440512);              // 33,554,432
    float*          F1   = (float*)(ws + 150994944);              // 33,554,432
    unsigned short* WtC2 = (unsigned short*)(ws + 184549376);     // 2,097,152
    unsigned short* Wt31 = (unsigned short*)(ws + 186646528);     // 1,179,648
    unsigned short* Wt32 = (unsigned short*)(ws + 187826176);
    unsigned short* Wt33 = (unsigned short*)(ws + 189005824);
    unsigned short* Wt34 = (unsigned short*)(ws + 190185472);
    unsigned short* W11  = (unsigned short*)(ws + 191365120);     // 131,072
    unsigned short* W12  = (unsigned short*)(ws + 191496192);
    unsigned short* W13  = (unsigned short*)(ws + 191627264);
    unsigned short* W14  = (unsigned short*)(ws + 191758336);
    unsigned short* WtT1 = (unsigned short*)(ws + 191889408);     // 2,097,152
    unsigned short* WtT2 = (unsigned short*)(ws + 193986560);     // 24,576
    float*          e2v  = (float*)(ws + 194011136);              // 2,048
    int*            lat  = (int*)(ws + 194013184);                // 131,072

    // weight transforms + e2
    k_e2<<<2, 256, 0, stream>>>(emb, e2v);
    k_wt16<<<4096, 256, 0, stream>>>(ec2w, WtC2, 4096, 16);
    k_wt16<<<4096, 256, 0, stream>>>(dt1w, WtT1, 16, 4096);
    k_wt3<<<dim3(2304, 4), 256, 0, stream>>>(er1w1, er2w1, dr1w1, dr2w1,
                                             Wt31, Wt32, Wt33, Wt34);
    k_wt1<<<dim3(256, 4), 256, 0, stream>>>(er1w2, er2w2, dr1w2, dr2w2,
                                            W11, W12, W13, W14);
    k_wt<<<48, 256, 0, stream>>>(dt2w, WtT2, 12288, 3, 256, 16, 48);

    // encoder
    k_conv1<<<dim3(16, 32), 256, 0, stream>>>(x, ec1w, ec1b, h1B);
    k_cgemm<0,true><<<dim3(2,8,32), 256, 0, stream>>>(h1B, WtC2, ec2b,
            nullptr, B0, F0, nullptr);
    k_cgemm<1,true><<<dim3(2,8,32), 256, 0, stream>>>(B0, Wt31, er1b1,
            nullptr, T3, nullptr, nullptr);
    k_cgemm<2,false><<<dim3(2,8,32), 256, 0, stream>>>(T3, W11, er1b2,
            F0, B1, F1, nullptr);
    k_cgemm<1,true><<<dim3(2,8,32), 256, 0, stream>>>(B1, Wt32, er2b1,
            nullptr, T3, nullptr, nullptr);
    k_cgemm<2,false><<<dim3(2,8,32), 256, 0, stream>>>(T3, W12, er2b2,
            F1, nullptr, nullptr, ze);
    // VQ
    k_vq<<<dim3(64,32), 256, 0, stream>>>(ze, emb, e2v, lat);
    k_gather<<<dim3(32,32), 256, 0, stream>>>(lat, emb, zq, B0, F0);
    // decoder
    k_cgemm<1,true><<<dim3(2,8,32), 256, 0, stream>>>(B0, Wt33, dr1b1,
            nullptr, T3, nullptr, nullptr);
    k_cgemm<2,false><<<dim3(2,8,32), 256, 0, stream>>>(T3, W13, dr1b2,
            F0, B1, F1, nullptr);
    k_cgemm<1,true><<<dim3(2,8,32), 256, 0, stream>>>(B1, Wt34, dr2b1,
            nullptr, T3, nullptr, nullptr);
    k_cgemm<2,false><<<dim3(2,8,32), 256, 0, stream>>>(T3, W14, dr2b2,
            F1, B0, nullptr, nullptr);
    k_cgemm<3,true><<<dim3(2,8,128), 256, 0, stream>>>(B0, WtT1, dt1b,
            nullptr, h1B, nullptr, nullptr);
    k_convt2<<<dim3(32,32), 256, 0, stream>>>(h1B, WtT2, dt2b, xt);
}

// Round 5
// 1224.543 us; speedup vs baseline: 1.6696x; 1.6696x over previous
//
#include <hip/hip_runtime.h>
#include <math.h>

using frag_ab = __attribute__((ext_vector_type(8))) short;
using f32x4   = __attribute__((ext_vector_type(4))) float;

__device__ __forceinline__ unsigned short f2b(float f) {
    unsigned u = __float_as_uint(f);
    u += 0x7fffu + ((u >> 16) & 1u);       // RNE
    return (unsigned short)(u >> 16);
}
__device__ __forceinline__ void bf8_to_f(uint4 v, float* f) {
    const unsigned* p = (const unsigned*)&v;
    #pragma unroll
    for (int q = 0; q < 4; ++q) {
        unsigned u = p[q];
        f[2*q]   = __uint_as_float(u << 16);
        f[2*q+1] = __uint_as_float(u & 0xffff0000u);
    }
}

// ---------------- weight transforms: out[tap][co][ci] bf16 ------------------
__global__ void k_wt(const float* __restrict__ in, unsigned short* __restrict__ out,
                     int total, int CO, int CI, int sO, int sI) {
    int i = blockIdx.x * 256 + threadIdx.x;
    if (i >= total) return;
    int ci = i % CI;
    int r  = i / CI;
    int co = r % CO;
    int tp = r / CO;
    out[i] = f2b(in[(size_t)co * sO + (size_t)ci * sI + tp]);
}
__global__ void k_wt16(const float* __restrict__ in, unsigned short* __restrict__ out,
                       int sO, int sI) {
    int i = blockIdx.x * 256 + threadIdx.x;      // < 16*65536
    int ci = i & 255, r = i >> 8;
    int co = r & 255, tp = r >> 8;
    out[i] = f2b(in[(size_t)co * sO + (size_t)ci * sI + tp]);
}
__global__ void k_wt3(const float* p0, const float* p1, const float* p2, const float* p3,
                      unsigned short* o0, unsigned short* o1, unsigned short* o2,
                      unsigned short* o3) {
    int z = blockIdx.y;
    const float* in = (z == 0) ? p0 : (z == 1) ? p1 : (z == 2) ? p2 : p3;
    unsigned short* out = (z == 0) ? o0 : (z == 1) ? o1 : (z == 2) ? o2 : o3;
    int i = blockIdx.x * 256 + threadIdx.x;      // < 9*65536
    int ci = i & 255, r = i >> 8;
    int co = r & 255, tp = r >> 8;
    out[i] = f2b(in[(size_t)co * 2304 + (size_t)ci * 9 + tp]);
}
__global__ void k_wt1(const float* p0, const float* p1, const float* p2, const float* p3,
                      unsigned short* o0, unsigned short* o1, unsigned short* o2,
                      unsigned short* o3) {
    int z = blockIdx.y;
    const float* in = (z == 0) ? p0 : (z == 1) ? p1 : (z == 2) ? p2 : p3;
    unsigned short* out = (z == 0) ? o0 : (z == 1) ? o1 : (z == 2) ? o2 : o3;
    int i = blockIdx.x * 256 + threadIdx.x;      // < 65536
    int ci = i & 255, co = i >> 8;
    out[i] = f2b(in[co * 256 + ci]);
}
// emb fp32 -> bf16 flat cast (131072 elems)
__global__ void k_embcast(const float* __restrict__ in, unsigned short* __restrict__ out) {
    int i = blockIdx.x * 256 + threadIdx.x;
    out[i] = f2b(in[i]);
}

// e2[k] = sum_d emb[k][d]^2
__global__ void k_e2(const float* __restrict__ emb, float* __restrict__ e2) {
    int k = blockIdx.x * 256 + threadIdx.x;
    if (k < 512) {
        const float* r = emb + k * 256;
        float s = 0.f;
        #pragma unroll 8
        for (int d = 0; d < 256; ++d) s += r[d] * r[d];
        e2[k] = s;
    }
}

// ---------------- conv1: 4x4 s2 p1, 3->256, 128->64, relu, NHWC bf16 out ----
__global__ __launch_bounds__(256) void k_conv1(const float* __restrict__ x,
        const float* __restrict__ w, const float* __restrict__ bias,
        unsigned short* __restrict__ out) {
    int t = threadIdx.x;
    int y = blockIdx.x * 4 + (t >> 6);
    int xq = t & 63;
    int b = blockIdx.y;
    float patch[48];
    #pragma unroll
    for (int ci = 0; ci < 3; ++ci)
        #pragma unroll
        for (int ky = 0; ky < 4; ++ky)
            #pragma unroll
            for (int kx = 0; kx < 4; ++kx) {
                int sy = 2*y - 1 + ky, sx = 2*xq - 1 + kx;
                float v = 0.f;
                if ((unsigned)sy < 128u && (unsigned)sx < 128u)
                    v = x[((b*3 + ci)*128 + sy)*128 + sx];
                patch[(ci*4 + ky)*4 + kx] = v;
            }
    unsigned short* op = out + (((size_t)(b*64 + y)*64 + xq) << 8);
    for (int c8 = 0; c8 < 32; ++c8) {
        unsigned short u8[8];
        #pragma unroll
        for (int cc = 0; cc < 8; ++cc) {
            int co = c8*8 + cc;
            float a = bias[co];
            #pragma unroll
            for (int k = 0; k < 48; ++k) a = fmaf(w[co*48 + k], patch[k], a);
            u8[cc] = f2b(fmaxf(a, 0.f));
        }
        *(uint4*)(op + c8*8) = *(uint4*)u8;
    }
}

// ---------------- unified implicit-GEMM conv (bf16 MFMA) --------------------
// block 256 = 4 waves; tile M=128 px x N=128 co; K staged in 128-ci chunks.
template<int MODE, bool RELU_OUT>
__global__ __launch_bounds__(256) void k_cgemm(
        const unsigned short* __restrict__ A,   // bf16 NHWC [B][Hin][Win][256]
        const unsigned short* __restrict__ Wt,  // bf16 [T][256co][256ci]
        const float* __restrict__ bias,
        const float* __restrict__ skipF,        // fp32 NHWC (nullable)
        unsigned short* __restrict__ outB,      // bf16 NHWC (nullable)
        float* __restrict__ outFn,              // fp32 NHWC (nullable)
        float* __restrict__ outFc) {            // fp32 NCHW 32x32 (nullable)
    constexpr int NTAPS = (MODE==0) ? 16 : (MODE==1) ? 9 : (MODE==2) ? 1 : 4;
    constexpr int HIN   = (MODE==0) ? 64 : 32;
    constexpr bool RELU_A = (MODE==1);
    constexpr bool ISCT   = (MODE==3);

    __shared__ __align__(16) unsigned short As[128*128];  // 32 KB
    __shared__ __align__(16) unsigned short Bs[128*128];  // 32 KB

    int t = threadIdx.x;
    int cob = blockIdx.x;            // 0..1 : co block of 128
    int y0  = blockIdx.y * 4;        // 4 out-rows in 32-grid
    int bz  = blockIdx.z;
    int b   = ISCT ? (bz >> 2) : bz;
    int par = ISCT ? (bz & 3) : 0;
    int psy = par >> 1, psx = par & 1;

    int scc = t & 15, sr0 = t >> 4;

    int wv = t >> 6, lane = t & 63;
    int mq = (wv >> 1) * 64, nq = (wv & 1) * 64;
    int lg = lane >> 4, lr = lane & 15;

    f32x4 acc[4][4];
    #pragma unroll
    for (int i = 0; i < 4; ++i)
        #pragma unroll
        for (int j = 0; j < 4; ++j) acc[i][j] = (f32x4){0.f,0.f,0.f,0.f};

    for (int tap = 0; tap < NTAPS; ++tap) {
        int tdy, tdx, wtap;
        if (MODE == 0)      { tdy = tap >> 2; tdx = tap & 3; wtap = tap; }
        else if (MODE == 1) { tdy = tap / 3;  tdx = tap % 3; wtap = tap; }
        else if (MODE == 2) { tdy = 0; tdx = 0; wtap = 0; }
        else { int jy = tap >> 1, jx = tap & 1;
               tdy = psy - jy; tdx = psx - jx;
               wtap = ((psy ? 0 : 1) + 2*jy) * 4 + ((psx ? 0 : 1) + 2*jx); }
        const unsigned short* wb = Wt + ((size_t)wtap << 16) + ((size_t)cob << 15);

        for (int half = 0; half < 2; ++half) {
            int kk0 = half * 128;
            __syncthreads();
            #pragma unroll
            for (int q = 0; q < 8; ++q) {
                int row = sr0 + 16*q;
                int soy = y0 + (row >> 5), sox = row & 31;
                int sy = (MODE == 0) ? (2*soy - 1 + tdy)
                       : (MODE == 1) ? (soy - 1 + tdy) : (soy + tdy);
                int sx = (MODE == 0) ? (2*sox - 1 + tdx)
                       : (MODE == 1) ? (sox - 1 + tdx) : (sox + tdx);
                bool val = ((unsigned)sy < (unsigned)HIN) && ((unsigned)sx < (unsigned)HIN);
                uint4 av = {0,0,0,0};
                if (val)
                    av = *(const uint4*)(A + ((((size_t)(b*HIN + sy))*HIN + sx) << 8)
                                           + kk0 + scc*8);
                if (RELU_A) {
                    unsigned* p = (unsigned*)&av;
                    #pragma unroll
                    for (int qq = 0; qq < 4; ++qq) {
                        unsigned s = p[qq] & 0x80008000u;
                        p[qq] &= ~((s >> 15) * 0xFFFFu);
                    }
                }
                *(uint4*)((char*)As + row*256 + ((scc ^ (row & 7)) << 4)) = av;
                uint4 bv = *(const uint4*)(wb + (((size_t)row) << 8) + kk0 + scc*8);
                *(uint4*)((char*)Bs + row*256 + ((scc ^ (row & 7)) << 4)) = bv;
            }
            __syncthreads();
            #pragma unroll
            for (int ks = 0; ks < 4; ++ks) {
                int c = ks*4 + lg;
                frag_ab af[4], bf[4];
                #pragma unroll
                for (int i = 0; i < 4; ++i) {
                    int ar = mq + i*16 + lr;
                    af[i] = *(const frag_ab*)((const char*)As + ar*256 + ((c ^ (ar & 7)) << 4));
                    int br = nq + i*16 + lr;
                    bf[i] = *(const frag_ab*)((const char*)Bs + br*256 + ((c ^ (br & 7)) << 4));
                }
                #pragma unroll
                for (int i = 0; i < 4; ++i)
                    #pragma unroll
                    for (int j = 0; j < 4; ++j)
                        acc[i][j] = __builtin_amdgcn_mfma_f32_16x16x32_bf16(
                                        af[i], bf[j], acc[i][j], 0, 0, 0);
            }
        }
    }

    #pragma unroll
    for (int mf = 0; mf < 4; ++mf) {
        #pragma unroll
        for (int nf = 0; nf < 4; ++nf) {
            int co = cob*128 + nq + nf*16 + lr;
            float bb = bias[co];
            f32x4 v = acc[mf][nf];
            #pragma unroll
            for (int j = 0; j < 4; ++j) {
                int prow = mq + mf*16 + lg*4 + j;
                int oy = y0 + (prow >> 5);
                int ox = prow & 31;
                size_t pix;
                if (ISCT) pix = ((size_t)(b*64 + (2*oy + psy)))*64 + (2*ox + psx);
                else      pix = ((size_t)(b*32 + oy))*32 + ox;
                float xv = v[j] + bb;
                if (skipF) xv += skipF[pix*256 + co];
                if (RELU_OUT) xv = fmaxf(xv, 0.f);
                if (outB)  outB[pix*256 + co] = f2b(xv);
                if (outFn) outFn[pix*256 + co] = xv;
                if (outFc) outFc[(((size_t)b*256 + co) << 10) + oy*32 + ox] = xv;
            }
        }
    }
}

// ---------------- VQ via MFMA: dots = Z_bf16 @ E_bf16^T, argmin epilogue ----
// block 256 = 4 waves, 64 positions; grid 512.  A once (32KB), B 8x64k chunks.
__global__ __launch_bounds__(256) void k_vqm(const unsigned short* __restrict__ zB,
        const unsigned short* __restrict__ eB,   // [512][256] bf16
        const float* __restrict__ e2, int* __restrict__ lat) {
    __shared__ __align__(16) unsigned short As[64*256];  // 32 KB, row=pos
    __shared__ __align__(16) unsigned short Bs[64*256];  // 32 KB, row=k-in-chunk
    int t = threadIdx.x;
    int pos0 = blockIdx.x * 64;
    // stage A (64 pos x 256 d), swizzled rows of 512B (32 chunks of 16B)
    #pragma unroll
    for (int q = 0; q < 8; ++q) {
        int idx = q*256 + t;
        int row = idx >> 5, ch = idx & 31;
        uint4 v = *(const uint4*)(zB + (((size_t)(pos0 + row)) << 8) + ch*8);
        *(uint4*)((char*)As + row*512 + ((ch ^ (row & 7)) << 4)) = v;
    }
    int wv = t >> 6, lane = t & 63;
    int lg = lane >> 4, lr = lane & 15;
    int arow = wv*16 + lr;
    int aswz[8];
    #pragma unroll
    for (int kk = 0; kk < 8; ++kk)
        aswz[kk] = arow*512 + (((kk*4 + lg) ^ (arow & 7)) << 4);
    float minv[4] = {1e30f, 1e30f, 1e30f, 1e30f};
    int   mink[4] = {0, 0, 0, 0};
    for (int kc = 0; kc < 8; ++kc) {
        __syncthreads();
        #pragma unroll
        for (int q = 0; q < 8; ++q) {
            int idx = q*256 + t;
            int row = idx >> 5, ch = idx & 31;
            uint4 v = *(const uint4*)(eB + (((size_t)(kc*64 + row)) << 8) + ch*8);
            *(uint4*)((char*)Bs + row*512 + ((ch ^ (row & 7)) << 4)) = v;
        }
        __syncthreads();
        #pragma unroll
        for (int nt = 0; nt < 4; ++nt) {
            int brow = nt*16 + lr;
            f32x4 acc = (f32x4){0.f, 0.f, 0.f, 0.f};
            #pragma unroll
            for (int kk = 0; kk < 8; ++kk) {
                frag_ab a = *(const frag_ab*)((const char*)As + aswz[kk]);
                frag_ab b = *(const frag_ab*)((const char*)Bs
                              + brow*512 + (((kk*4 + lg) ^ (brow & 7)) << 4));
                acc = __builtin_amdgcn_mfma_f32_16x16x32_bf16(a, b, acc, 0, 0, 0);
            }
            int k = kc*64 + nt*16 + lr;
            float ee = e2[k];
            #pragma unroll
            for (int j = 0; j < 4; ++j) {
                float dist = ee - 2.f * acc[j];
                if (dist < minv[j]) { minv[j] = dist; mink[j] = k; }
            }
        }
    }
    // reduce across the 16 k-columns (lanes sharing lg)
    #pragma unroll
    for (int s = 1; s < 16; s <<= 1) {
        #pragma unroll
        for (int j = 0; j < 4; ++j) {
            float ov = __shfl_xor(minv[j], s, 64);
            int   ok = __shfl_xor(mink[j], s, 64);
            if (ov < minv[j] || (ov == minv[j] && ok < mink[j])) {
                minv[j] = ov; mink[j] = ok;
            }
        }
    }
    if (lr == 0) {
        #pragma unroll
        for (int j = 0; j < 4; ++j)
            lat[pos0 + wv*16 + lg*4 + j] = mink[j];
    }
}

// gather: zq NCHW fp32 (d_out) + NHWC bf16 + NHWC fp32
__global__ __launch_bounds__(256) void k_gather(const int* __restrict__ lat,
        const float* __restrict__ emb, float* __restrict__ zqc,
        unsigned short* __restrict__ zqB, float* __restrict__ zqF) {
    __shared__ int ll[32];
    int t = threadIdx.x, y = blockIdx.x, b = blockIdx.y;
    if (t < 32) ll[t] = lat[(b * 32 + y) * 32 + t];
    __syncthreads();
    #pragma unroll
    for (int i = 0; i < 32; ++i) {
        int l = i * 256 + t;
        int d = l >> 5, xx = l & 31;
        zqc[(((size_t)b*256 + d) << 10) + y*32 + xx] = emb[ll[xx]*256 + d];
    }
    int xx = t & 31, dg = t >> 5;
    const float* e = emb + ll[xx]*256 + dg*32;
    size_t off = ((((size_t)(b*32 + y)*32 + xx)) << 8) + dg*32;
    #pragma unroll
    for (int q = 0; q < 8; ++q) {
        float4 v = *(const float4*)(e + q*4);
        *(float4*)(zqF + off + q*4) = v;
        uint2 pk;
        pk.x = (unsigned)f2b(v.x) | ((unsigned)f2b(v.y) << 16);
        pk.y = (unsigned)f2b(v.z) | ((unsigned)f2b(v.w) << 16);
        *(uint2*)(zqB + off + q*4) = pk;
    }
}

// ---------------- convT2: 4x4 s2 p1, 256->3, 64->128, sigmoid, NCHW fp32 ----
__global__ __launch_bounds__(256) void k_convt2(const unsigned short* __restrict__ in,
        const unsigned short* __restrict__ Wt,  // [16][3][256] bf16
        const float* __restrict__ bias, float* __restrict__ out) {
    __shared__ __align__(16) unsigned short slab[4*66*32];
    __shared__ __align__(16) unsigned short wl[16*3*32];
    int t = threadIdx.x;
    int b = blockIdx.y;
    int oy0 = blockIdx.x * 4;
    int u0 = oy0 >> 1;
    int oyl = t >> 7, ox = t & 127;
    int sy = oyl & 1, sx = ox & 1;
    int v = ox >> 1;
    float acc0[3] = {0.f,0.f,0.f}, acc1[3] = {0.f,0.f,0.f};
    for (int kc = 0; kc < 8; ++kc) {
        __syncthreads();
        for (int i = t; i < 4*66*4; i += 256) {
            int g = i & 3; int cidx = i >> 2;
            int cc = cidx % 66, ri = cidx / 66;
            int iy = u0 - 1 + ri, ix = cc - 1;
            uint4 v4 = {0,0,0,0};
            if ((unsigned)iy < 64u && (unsigned)ix < 64u)
                v4 = *(const uint4*)(in + (((size_t)(b*64 + iy)*64 + ix) << 8)
                                        + kc*32 + g*8);
            *(uint4*)(&slab[(ri*66 + cc)*32 + g*8]) = v4;
        }
        for (int i = t; i < 1536; i += 256)
            wl[i] = Wt[(i >> 5) * 256 + kc*32 + (i & 31)];
        __syncthreads();
        #pragma unroll
        for (int jy = 0; jy < 2; ++jy) {
            int duy = sy - jy;
            int riA = 1 + duy;
            #pragma unroll
            for (int jx = 0; jx < 2; ++jx) {
                int dvx = sx - jx;
                int cc = v + dvx + 1;
                int wtap = ((sy ? 0 : 1) + 2*jy)*4 + ((sx ? 0 : 1) + 2*jx);
                const unsigned short* sA = &slab[(riA*66 + cc)*32];
                const unsigned short* sB = sA + 66*32;
                const unsigned short* wp = &wl[wtap*96];
                #pragma unroll
                for (int c8 = 0; c8 < 4; ++c8) {
                    float fA[8], fB[8], w0[8], w1[8], w2[8];
                    bf8_to_f(*(const uint4*)(sA + c8*8), fA);
                    bf8_to_f(*(const uint4*)(sB + c8*8), fB);
                    bf8_to_f(*(const uint4*)(wp + c8*8), w0);
                    bf8_to_f(*(const uint4*)(wp + 32 + c8*8), w1);
                    bf8_to_f(*(const uint4*)(wp + 64 + c8*8), w2);
                    #pragma unroll
                    for (int q = 0; q < 8; ++q) {
                        acc0[0] = fmaf(fA[q], w0[q], acc0[0]);
                        acc0[1] = fmaf(fA[q], w1[q], acc0[1]);
                        acc0[2] = fmaf(fA[q], w2[q], acc0[2]);
                        acc1[0] = fmaf(fB[q], w0[q], acc1[0]);
                        acc1[1] = fmaf(fB[q], w1[q], acc1[1]);
                        acc1[2] = fmaf(fB[q], w2[q], acc1[2]);
                    }
                }
            }
        }
    }
    #pragma unroll
    for (int co = 0; co < 3; ++co) {
        float b0 = acc0[co] + bias[co];
        float b1 = acc1[co] + bias[co];
        out[(((size_t)b*3 + co) << 14) + (oy0 + oyl)*128 + ox]     = 1.f/(1.f + __expf(-b0));
        out[(((size_t)b*3 + co) << 14) + (oy0 + oyl + 2)*128 + ox] = 1.f/(1.f + __expf(-b1));
    }
}

extern "C" void kernel_launch(void* const* d_in, const int* in_sizes, int n_in,
                              void* d_out, int out_size, void* d_ws, size_t ws_size,
                              hipStream_t stream) {
    const float* x     = (const float*)d_in[0];
    const float* ec1w  = (const float*)d_in[1];
    const float* ec1b  = (const float*)d_in[2];
    const float* ec2w  = (const float*)d_in[3];
    const float* ec2b  = (const float*)d_in[4];
    const float* er1w1 = (const float*)d_in[5];
    const float* er1b1 = (const float*)d_in[6];
    const float* er1w2 = (const float*)d_in[7];
    const float* er1b2 = (const float*)d_in[8];
    const float* er2w1 = (const float*)d_in[9];
    const float* er2b1 = (const float*)d_in[10];
    const float* er2w2 = (const float*)d_in[11];
    const float* er2b2 = (const float*)d_in[12];
    const float* emb   = (const float*)d_in[13];
    const float* dr1w1 = (const float*)d_in[14];
    const float* dr1b1 = (const float*)d_in[15];
    const float* dr1w2 = (const float*)d_in[16];
    const float* dr1b2 = (const float*)d_in[17];
    const float* dr2w1 = (const float*)d_in[18];
    const float* dr2b1 = (const float*)d_in[19];
    const float* dr2w2 = (const float*)d_in[20];
    const float* dr2b2 = (const float*)d_in[21];
    const float* dt1w  = (const float*)d_in[22];
    const float* dt1b  = (const float*)d_in[23];
    const float* dt2w  = (const float*)d_in[24];
    const float* dt2b  = (const float*)d_in[25];

    float* outp = (float*)d_out;
    float* xt = outp;                    // x_tilde 1,572,864
    float* ze = outp + 1572864;          // z_e_x   8,388,608
    float* zq = ze + 8388608;            // z_q_x   8,388,608

    char* ws = (char*)d_ws;
    unsigned short* h1B  = (unsigned short*)(ws);                 // 67,108,864 B
    unsigned short* B0   = (unsigned short*)(ws + 67108864);      // 16,777,216
    unsigned short* B1   = (unsigned short*)(ws + 83886080);      // 16,777,216
    unsigned short* T3   = (unsigned short*)(ws + 100663296);     // 16,777,216
    float*          F0   = (float*)(ws + 117440512);              // 33,554,432
    float*          F1   = (float*)(ws + 150994944);              // 33,554,432
    unsigned short* WtC2 = (unsigned short*)(ws + 184549376);     // 2,097,152
    unsigned short* Wt31 = (unsigned short*)(ws + 186646528);     // 1,179,648
    unsigned short* Wt32 = (unsigned short*)(ws + 187826176);
    unsigned short* Wt33 = (unsigned short*)(ws + 189005824);
    unsigned short* Wt34 = (unsigned short*)(ws + 190185472);
    unsigned short* W11  = (unsigned short*)(ws + 191365120);     // 131,072
    unsigned short* W12  = (unsigned short*)(ws + 191496192);
    unsigned short* W13  = (unsigned short*)(ws + 191627264);
    unsigned short* W14  = (unsigned short*)(ws + 191758336);
    unsigned short* WtT1 = (unsigned short*)(ws + 191889408);     // 2,097,152
    unsigned short* WtT2 = (unsigned short*)(ws + 193986560);     // 24,576
    float*          e2v  = (float*)(ws + 194011136);              // 2,048
    int*            lat  = (int*)(ws + 194013184);                // 131,072
    unsigned short* embB = (unsigned short*)(ws + 194144256);     // 262,144

    // weight transforms + e2 + emb cast
    k_e2<<<2, 256, 0, stream>>>(emb, e2v);
    k_embcast<<<512, 256, 0, stream>>>(emb, embB);
    k_wt16<<<4096, 256, 0, stream>>>(ec2w, WtC2, 4096, 16);
    k_wt16<<<4096, 256, 0, stream>>>(dt1w, WtT1, 16, 4096);
    k_wt3<<<dim3(2304, 4), 256, 0, stream>>>(er1w1, er2w1, dr1w1, dr2w1,
                                             Wt31, Wt32, Wt33, Wt34);
    k_wt1<<<dim3(256, 4), 256, 0, stream>>>(er1w2, er2w2, dr1w2, dr2w2,
                                            W11, W12, W13, W14);
    k_wt<<<48, 256, 0, stream>>>(dt2w, WtT2, 12288, 3, 256, 16, 48);

    // encoder
    k_conv1<<<dim3(16, 32), 256, 0, stream>>>(x, ec1w, ec1b, h1B);
    k_cgemm<0,true><<<dim3(2,8,32), 256, 0, stream>>>(h1B, WtC2, ec2b,
            nullptr, B0, F0, nullptr);
    k_cgemm<1,true><<<dim3(2,8,32), 256, 0, stream>>>(B0, Wt31, er1b1,
            nullptr, T3, nullptr, nullptr);
    k_cgemm<2,false><<<dim3(2,8,32), 256, 0, stream>>>(T3, W11, er1b2,
            F0, B1, F1, nullptr);
    k_cgemm<1,true><<<dim3(2,8,32), 256, 0, stream>>>(B1, Wt32, er2b1,
            nullptr, T3, nullptr, nullptr);
    k_cgemm<2,false><<<dim3(2,8,32), 256, 0, stream>>>(T3, W12, er2b2,
            F1, B0, nullptr, ze);
    // VQ (MFMA) + gather
    k_vqm<<<512, 256, 0, stream>>>(B0, embB, e2v, lat);
    k_gather<<<dim3(32,32), 256, 0, stream>>>(lat, emb, zq, B0, F0);
    // decoder
    k_cgemm<1,true><<<dim3(2,8,32), 256, 0, stream>>>(B0, Wt33, dr1b1,
            nullptr, T3, nullptr, nullptr);
    k_cgemm<2,false><<<dim3(2,8,32), 256, 0, stream>>>(T3, W13, dr1b2,
            F0, B1, F1, nullptr);
    k_cgemm<1,true><<<dim3(2,8,32), 256, 0, stream>>>(B1, Wt34, dr2b1,
            nullptr, T3, nullptr, nullptr);
    k_cgemm<2,false><<<dim3(2,8,32), 256, 0, stream>>>(T3, W14, dr2b2,
            F1, B0, nullptr, nullptr);
    k_cgemm<3,true><<<dim3(2,8,128), 256, 0, stream>>>(B0, WtT1, dt1b,
            nullptr, h1B, nullptr, nullptr);
    k_convt2<<<dim3(32,32), 256, 0, stream>>>(h1B, WtT2, dt2b, xt);
}

// Round 6
// 1001.287 us; speedup vs baseline: 2.0419x; 1.2230x over previous
//
#include <hip/hip_runtime.h>
#include <math.h>

using frag_ab = __attribute__((ext_vector_type(8))) short;
using f32x4   = __attribute__((ext_vector_type(4))) float;

__device__ __forceinline__ unsigned short f2b(float f) {
    unsigned u = __float_as_uint(f);
    u += 0x7fffu + ((u >> 16) & 1u);       // RNE
    return (unsigned short)(u >> 16);
}
__device__ __forceinline__ void bf8_to_f(uint4 v, float* f) {
    const unsigned* p = (const unsigned*)&v;
    #pragma unroll
    for (int q = 0; q < 4; ++q) {
        unsigned u = p[q];
        f[2*q]   = __uint_as_float(u << 16);
        f[2*q+1] = __uint_as_float(u & 0xffff0000u);
    }
}
// async 16B global->LDS (dest must be wave-uniform-base + lane*16 linear)
__device__ __forceinline__ void gload16(const void* g, void* l) {
    __builtin_amdgcn_global_load_lds(g, l, 16, 0, 0);
}

// ---------------- weight transforms: out[tap][co][ci] bf16 ------------------
__global__ void k_wt(const float* __restrict__ in, unsigned short* __restrict__ out,
                     int total, int CO, int CI, int sO, int sI) {
    int i = blockIdx.x * 256 + threadIdx.x;
    if (i >= total) return;
    int ci = i % CI;
    int r  = i / CI;
    int co = r % CO;
    int tp = r / CO;
    out[i] = f2b(in[(size_t)co * sO + (size_t)ci * sI + tp]);
}
// 16-tap 256x256: thread streams 16 consecutive floats, writes coalesced
__global__ void k_wt16(const float* __restrict__ in, unsigned short* __restrict__ out,
                       int sO, int sI) {
    int i = blockIdx.x * 256 + threadIdx.x;      // < 65536 : i = co*256+ci
    int ci = i & 255, co = i >> 8;
    const float* p = in + (size_t)co * sO + (size_t)ci * sI;
    #pragma unroll
    for (int tp = 0; tp < 16; ++tp)
        out[tp * 65536 + i] = f2b(p[tp]);
}
// 4x fused 3x3 256x256
__global__ void k_wt3(const float* p0, const float* p1, const float* p2, const float* p3,
                      unsigned short* o0, unsigned short* o1, unsigned short* o2,
                      unsigned short* o3) {
    int z = blockIdx.y;
    const float* in = (z == 0) ? p0 : (z == 1) ? p1 : (z == 2) ? p2 : p3;
    unsigned short* out = (z == 0) ? o0 : (z == 1) ? o1 : (z == 2) ? o2 : o3;
    int i = blockIdx.x * 256 + threadIdx.x;      // < 65536
    int ci = i & 255, co = i >> 8;
    const float* p = in + (size_t)co * 2304 + (size_t)ci * 9;
    #pragma unroll
    for (int tp = 0; tp < 9; ++tp)
        out[tp * 65536 + i] = f2b(p[tp]);
}
// 4x fused 1x1 256x256
__global__ void k_wt1(const float* p0, const float* p1, const float* p2, const float* p3,
                      unsigned short* o0, unsigned short* o1, unsigned short* o2,
                      unsigned short* o3) {
    int z = blockIdx.y;
    const float* in = (z == 0) ? p0 : (z == 1) ? p1 : (z == 2) ? p2 : p3;
    unsigned short* out = (z == 0) ? o0 : (z == 1) ? o1 : (z == 2) ? o2 : o3;
    int i = blockIdx.x * 256 + threadIdx.x;      // < 65536
    int ci = i & 255, co = i >> 8;
    out[i] = f2b(in[co * 256 + ci]);
}
// emb fp32 -> bf16 flat cast
__global__ void k_embcast(const float* __restrict__ in, unsigned short* __restrict__ out) {
    int i = blockIdx.x * 256 + threadIdx.x;
    out[i] = f2b(in[i]);
}

// e2[k] = sum_d emb[k][d]^2 ; block 2 zeroes the OOB zero-page
__global__ void k_e2(const float* __restrict__ emb, float* __restrict__ e2,
                     float* __restrict__ zpad) {
    if (blockIdx.x == 2) { zpad[threadIdx.x] = 0.f; return; }
    int k = blockIdx.x * 256 + threadIdx.x;
    if (k < 512) {
        const float* r = emb + k * 256;
        float s = 0.f;
        #pragma unroll 8
        for (int d = 0; d < 256; ++d) s += r[d] * r[d];
        e2[k] = s;
    }
}

// ---------------- conv1: 4x4 s2 p1, 3->256, 128->64, relu, NHWC bf16 out ----
// grid (16 ytiles, 32 b, 4 co-blocks); 64 co per block for occupancy
__global__ __launch_bounds__(256) void k_conv1(const float* __restrict__ x,
        const float* __restrict__ w, const float* __restrict__ bias,
        unsigned short* __restrict__ out) {
    int t = threadIdx.x;
    int y = blockIdx.x * 4 + (t >> 6);
    int xq = t & 63;
    int b = blockIdx.y;
    int co0 = blockIdx.z * 64;
    float patch[48];
    #pragma unroll
    for (int ci = 0; ci < 3; ++ci)
        #pragma unroll
        for (int ky = 0; ky < 4; ++ky)
            #pragma unroll
            for (int kx = 0; kx < 4; ++kx) {
                int sy = 2*y - 1 + ky, sx = 2*xq - 1 + kx;
                float v = 0.f;
                if ((unsigned)sy < 128u && (unsigned)sx < 128u)
                    v = x[((b*3 + ci)*128 + sy)*128 + sx];
                patch[(ci*4 + ky)*4 + kx] = v;
            }
    unsigned short* op = out + (((size_t)(b*64 + y)*64 + xq) << 8) + co0;
    for (int c8 = 0; c8 < 8; ++c8) {
        unsigned short u8[8];
        #pragma unroll
        for (int cc = 0; cc < 8; ++cc) {
            int co = co0 + c8*8 + cc;
            float a = bias[co];
            #pragma unroll
            for (int k = 0; k < 48; ++k) a = fmaf(w[co*48 + k], patch[k], a);
            u8[cc] = f2b(fmaxf(a, 0.f));
        }
        *(uint4*)(op + c8*8) = *(uint4*)u8;
    }
}

// ---------------- unified implicit-GEMM conv (bf16 MFMA) --------------------
// block 256 = 4 waves; tile M=128 px x N=128 co; K staged in 128-ci chunks via
// global_load_lds (pure copy; swizzle applied on SOURCE address, LDS linear).
template<int MODE, bool RELU_OUT, bool RELU_B16>
__global__ __launch_bounds__(256) void k_cgemm(
        const unsigned short* __restrict__ A,   // bf16 NHWC [B][Hin][Win][256]
        const unsigned short* __restrict__ Wt,  // bf16 [T][256co][256ci]
        const float* __restrict__ bias,
        const float* __restrict__ skipF,        // fp32 NHWC (nullable)
        const unsigned short* __restrict__ zpad,// >=16B zeros (OOB source)
        unsigned short* __restrict__ outB,      // bf16 NHWC (nullable)
        float* __restrict__ outFn,              // fp32 NHWC (nullable)
        float* __restrict__ outFc) {            // fp32 NCHW 32x32 (nullable)
    constexpr int NTAPS = (MODE==0) ? 16 : (MODE==1) ? 9 : (MODE==2) ? 1 : 4;
    constexpr int HIN   = (MODE==0) ? 64 : 32;
    constexpr bool ISCT   = (MODE==3);

    __shared__ __align__(16) unsigned short As[128*128];  // 32 KB
    __shared__ __align__(16) unsigned short Bs[128*128];  // 32 KB

    int t = threadIdx.x;
    int cob = blockIdx.x;            // 0..1 : co block of 128
    int y0  = blockIdx.y * 4;        // 4 out-rows in 32-grid
    int bz  = blockIdx.z;
    int b   = ISCT ? (bz >> 2) : bz;
    int par = ISCT ? (bz & 3) : 0;
    int psy = par >> 1, psx = par & 1;

    int scc = t & 15, sr0 = t >> 4;
    int sc2 = scc ^ (sr0 & 7);       // inverse-swizzled source chunk (involution)

    int wv = t >> 6, lane = t & 63;
    int mq = (wv >> 1) * 64, nq = (wv & 1) * 64;
    int lg = lane >> 4, lr = lane & 15;

    f32x4 acc[4][4];
    #pragma unroll
    for (int i = 0; i < 4; ++i)
        #pragma unroll
        for (int j = 0; j < 4; ++j) acc[i][j] = (f32x4){0.f,0.f,0.f,0.f};

    for (int tap = 0; tap < NTAPS; ++tap) {
        int tdy, tdx, wtap;
        if (MODE == 0)      { tdy = tap >> 2; tdx = tap & 3; wtap = tap; }
        else if (MODE == 1) { tdy = tap / 3;  tdx = tap % 3; wtap = tap; }
        else if (MODE == 2) { tdy = 0; tdx = 0; wtap = 0; }
        else { int jy = tap >> 1, jx = tap & 1;
               tdy = psy - jy; tdx = psx - jx;
               wtap = ((psy ? 0 : 1) + 2*jy) * 4 + ((psx ? 0 : 1) + 2*jx); }
        const unsigned short* wb = Wt + ((size_t)wtap << 16) + ((size_t)cob << 15);

        for (int half = 0; half < 2; ++half) {
            int kk0 = half * 128;
            __syncthreads();
            #pragma unroll
            for (int q = 0; q < 8; ++q) {
                int row = sr0 + 16*q;
                int soy = y0 + (row >> 5), sox = row & 31;
                int sy = (MODE == 0) ? (2*soy - 1 + tdy)
                       : (MODE == 1) ? (soy - 1 + tdy) : (soy + tdy);
                int sx = (MODE == 0) ? (2*sox - 1 + tdx)
                       : (MODE == 1) ? (sox - 1 + tdx) : (sox + tdx);
                bool val = ((unsigned)sy < (unsigned)HIN) && ((unsigned)sx < (unsigned)HIN);
                const unsigned short* asrc = val
                    ? A + ((((size_t)(b*HIN + sy))*HIN + sx) << 8) + kk0 + sc2*8
                    : zpad;
                gload16(asrc, (char*)As + q*4096 + t*16);
                gload16(wb + (((size_t)row) << 8) + kk0 + sc2*8,
                        (char*)Bs + q*4096 + t*16);
            }
            __syncthreads();
            #pragma unroll
            for (int ks = 0; ks < 4; ++ks) {
                int c = ks*4 + lg;
                frag_ab af[4], bf[4];
                #pragma unroll
                for (int i = 0; i < 4; ++i) {
                    int ar = mq + i*16 + lr;
                    af[i] = *(const frag_ab*)((const char*)As + ar*256 + ((c ^ (ar & 7)) << 4));
                    int br = nq + i*16 + lr;
                    bf[i] = *(const frag_ab*)((const char*)Bs + br*256 + ((c ^ (br & 7)) << 4));
                }
                #pragma unroll
                for (int i = 0; i < 4; ++i)
                    #pragma unroll
                    for (int j = 0; j < 4; ++j)
                        acc[i][j] = __builtin_amdgcn_mfma_f32_16x16x32_bf16(
                                        af[i], bf[j], acc[i][j], 0, 0, 0);
            }
        }
    }

    #pragma unroll
    for (int mf = 0; mf < 4; ++mf) {
        #pragma unroll
        for (int nf = 0; nf < 4; ++nf) {
            int co = cob*128 + nq + nf*16 + lr;
            float bb = bias[co];
            f32x4 v = acc[mf][nf];
            #pragma unroll
            for (int j = 0; j < 4; ++j) {
                int prow = mq + mf*16 + lg*4 + j;
                int oy = y0 + (prow >> 5);
                int ox = prow & 31;
                size_t pix;
                if (ISCT) pix = ((size_t)(b*64 + (2*oy + psy)))*64 + (2*ox + psx);
                else      pix = ((size_t)(b*32 + oy))*32 + ox;
                float xv = v[j] + bb;
                if (skipF) xv += skipF[pix*256 + co];
                if (RELU_OUT) xv = fmaxf(xv, 0.f);
                if (outB)  outB[pix*256 + co] = f2b(RELU_B16 ? fmaxf(xv, 0.f) : xv);
                if (outFn) outFn[pix*256 + co] = xv;
                if (outFc) outFc[(((size_t)b*256 + co) << 10) + oy*32 + ox] = xv;
            }
        }
    }
}

// ---------------- VQ via MFMA: dots = Z_bf16 @ E_bf16^T, argmin epilogue ----
__global__ __launch_bounds__(256) void k_vqm(const unsigned short* __restrict__ zB,
        const unsigned short* __restrict__ eB,   // [512][256] bf16
        const float* __restrict__ e2, int* __restrict__ lat) {
    __shared__ __align__(16) unsigned short As[64*256];  // 32 KB, row=pos
    __shared__ __align__(16) unsigned short Bs[64*256];  // 32 KB, row=k-in-chunk
    int t = threadIdx.x;
    int pos0 = blockIdx.x * 64;
    #pragma unroll
    for (int q = 0; q < 8; ++q) {
        int idx = q*256 + t;
        int row = idx >> 5, ch = idx & 31;
        uint4 v = *(const uint4*)(zB + (((size_t)(pos0 + row)) << 8) + ch*8);
        *(uint4*)((char*)As + row*512 + ((ch ^ (row & 7)) << 4)) = v;
    }
    int wv = t >> 6, lane = t & 63;
    int lg = lane >> 4, lr = lane & 15;
    int arow = wv*16 + lr;
    int aswz[8];
    #pragma unroll
    for (int kk = 0; kk < 8; ++kk)
        aswz[kk] = arow*512 + (((kk*4 + lg) ^ (arow & 7)) << 4);
    float minv[4] = {1e30f, 1e30f, 1e30f, 1e30f};
    int   mink[4] = {0, 0, 0, 0};
    for (int kc = 0; kc < 8; ++kc) {
        __syncthreads();
        #pragma unroll
        for (int q = 0; q < 8; ++q) {
            int idx = q*256 + t;
            int row = idx >> 5, ch = idx & 31;
            uint4 v = *(const uint4*)(eB + (((size_t)(kc*64 + row)) << 8) + ch*8);
            *(uint4*)((char*)Bs + row*512 + ((ch ^ (row & 7)) << 4)) = v;
        }
        __syncthreads();
        #pragma unroll
        for (int nt = 0; nt < 4; ++nt) {
            int brow = nt*16 + lr;
            f32x4 acc = (f32x4){0.f, 0.f, 0.f, 0.f};
            #pragma unroll
            for (int kk = 0; kk < 8; ++kk) {
                frag_ab a = *(const frag_ab*)((const char*)As + aswz[kk]);
                frag_ab b = *(const frag_ab*)((const char*)Bs
                              + brow*512 + (((kk*4 + lg) ^ (brow & 7)) << 4));
                acc = __builtin_amdgcn_mfma_f32_16x16x32_bf16(a, b, acc, 0, 0, 0);
            }
            int k = kc*64 + nt*16 + lr;
            float ee = e2[k];
            #pragma unroll
            for (int j = 0; j < 4; ++j) {
                float dist = ee - 2.f * acc[j];
                if (dist < minv[j]) { minv[j] = dist; mink[j] = k; }
            }
        }
    }
    #pragma unroll
    for (int s = 1; s < 16; s <<= 1) {
        #pragma unroll
        for (int j = 0; j < 4; ++j) {
            float ov = __shfl_xor(minv[j], s, 64);
            int   ok = __shfl_xor(mink[j], s, 64);
            if (ov < minv[j] || (ov == minv[j] && ok < mink[j])) {
                minv[j] = ov; mink[j] = ok;
            }
        }
    }
    if (lr == 0) {
        #pragma unroll
        for (int j = 0; j < 4; ++j)
            lat[pos0 + wv*16 + lg*4 + j] = mink[j];
    }
}

// gather: zq NCHW fp32 (d_out, raw) + NHWC bf16 (RELU'd, for 3x3) + NHWC fp32 (raw skip)
__global__ __launch_bounds__(256) void k_gather(const int* __restrict__ lat,
        const float* __restrict__ emb, float* __restrict__ zqc,
        unsigned short* __restrict__ zqB, float* __restrict__ zqF) {
    __shared__ int ll[32];
    int t = threadIdx.x, y = blockIdx.x, b = blockIdx.y;
    if (t < 32) ll[t] = lat[(b * 32 + y) * 32 + t];
    __syncthreads();
    #pragma unroll
    for (int i = 0; i < 32; ++i) {
        int l = i * 256 + t;
        int d = l >> 5, xx = l & 31;
        zqc[(((size_t)b*256 + d) << 10) + y*32 + xx] = emb[ll[xx]*256 + d];
    }
    int xx = t & 31, dg = t >> 5;
    const float* e = emb + ll[xx]*256 + dg*32;
    size_t off = ((((size_t)(b*32 + y)*32 + xx)) << 8) + dg*32;
    #pragma unroll
    for (int q = 0; q < 8; ++q) {
        float4 v = *(const float4*)(e + q*4);
        *(float4*)(zqF + off + q*4) = v;
        uint2 pk;
        pk.x = (unsigned)f2b(fmaxf(v.x, 0.f)) | ((unsigned)f2b(fmaxf(v.y, 0.f)) << 16);
        pk.y = (unsigned)f2b(fmaxf(v.z, 0.f)) | ((unsigned)f2b(fmaxf(v.w, 0.f)) << 16);
        *(uint2*)(zqB + off + q*4) = pk;
    }
}

// ---------------- convT2: 4x4 s2 p1, 256->3, 64->128, sigmoid, NCHW fp32 ----
__global__ __launch_bounds__(256) void k_convt2(const unsigned short* __restrict__ in,
        const unsigned short* __restrict__ Wt,  // [16][3][256] bf16
        const float* __restrict__ bias, float* __restrict__ out) {
    __shared__ __align__(16) unsigned short slab[4*66*32];
    __shared__ __align__(16) unsigned short wl[16*3*32];
    int t = threadIdx.x;
    int b = blockIdx.y;
    int oy0 = blockIdx.x * 4;
    int u0 = oy0 >> 1;
    int oyl = t >> 7, ox = t & 127;
    int sy = oyl & 1, sx = ox & 1;
    int v = ox >> 1;
    float acc0[3] = {0.f,0.f,0.f}, acc1[3] = {0.f,0.f,0.f};
    for (int kc = 0; kc < 8; ++kc) {
        __syncthreads();
        for (int i = t; i < 4*66*4; i += 256) {
            int g = i & 3; int cidx = i >> 2;
            int cc = cidx % 66, ri = cidx / 66;
            int iy = u0 - 1 + ri, ix = cc - 1;
            uint4 v4 = {0,0,0,0};
            if ((unsigned)iy < 64u && (unsigned)ix < 64u)
                v4 = *(const uint4*)(in + (((size_t)(b*64 + iy)*64 + ix) << 8)
                                        + kc*32 + g*8);
            *(uint4*)(&slab[(ri*66 + cc)*32 + g*8]) = v4;
        }
        for (int i = t; i < 1536; i += 256)
            wl[i] = Wt[(i >> 5) * 256 + kc*32 + (i & 31)];
        __syncthreads();
        #pragma unroll
        for (int jy = 0; jy < 2; ++jy) {
            int duy = sy - jy;
            int riA = 1 + duy;
            #pragma unroll
            for (int jx = 0; jx < 2; ++jx) {
                int dvx = sx - jx;
                int cc = v + dvx + 1;
                int wtap = ((sy ? 0 : 1) + 2*jy)*4 + ((sx ? 0 : 1) + 2*jx);
                const unsigned short* sA = &slab[(riA*66 + cc)*32];
                const unsigned short* sB = sA + 66*32;
                const unsigned short* wp = &wl[wtap*96];
                #pragma unroll
                for (int c8 = 0; c8 < 4; ++c8) {
                    float fA[8], fB[8], w0[8], w1[8], w2[8];
                    bf8_to_f(*(const uint4*)(sA + c8*8), fA);
                    bf8_to_f(*(const uint4*)(sB + c8*8), fB);
                    bf8_to_f(*(const uint4*)(wp + c8*8), w0);
                    bf8_to_f(*(const uint4*)(wp + 32 + c8*8), w1);
                    bf8_to_f(*(const uint4*)(wp + 64 + c8*8), w2);
                    #pragma unroll
                    for (int q = 0; q < 8; ++q) {
                        acc0[0] = fmaf(fA[q], w0[q], acc0[0]);
                        acc0[1] = fmaf(fA[q], w1[q], acc0[1]);
                        acc0[2] = fmaf(fA[q], w2[q], acc0[2]);
                        acc1[0] = fmaf(fB[q], w0[q], acc1[0]);
                        acc1[1] = fmaf(fB[q], w1[q], acc1[1]);
                        acc1[2] = fmaf(fB[q], w2[q], acc1[2]);
                    }
                }
            }
        }
    }
    #pragma unroll
    for (int co = 0; co < 3; ++co) {
        float b0 = acc0[co] + bias[co];
        float b1 = acc1[co] + bias[co];
        out[(((size_t)b*3 + co) << 14) + (oy0 + oyl)*128 + ox]     = 1.f/(1.f + __expf(-b0));
        out[(((size_t)b*3 + co) << 14) + (oy0 + oyl + 2)*128 + ox] = 1.f/(1.f + __expf(-b1));
    }
}

extern "C" void kernel_launch(void* const* d_in, const int* in_sizes, int n_in,
                              void* d_out, int out_size, void* d_ws, size_t ws_size,
                              hipStream_t stream) {
    const float* x     = (const float*)d_in[0];
    const float* ec1w  = (const float*)d_in[1];
    const float* ec1b  = (const float*)d_in[2];
    const float* ec2w  = (const float*)d_in[3];
    const float* ec2b  = (const float*)d_in[4];
    const float* er1w1 = (const float*)d_in[5];
    const float* er1b1 = (const float*)d_in[6];
    const float* er1w2 = (const float*)d_in[7];
    const float* er1b2 = (const float*)d_in[8];
    const float* er2w1 = (const float*)d_in[9];
    const float* er2b1 = (const float*)d_in[10];
    const float* er2w2 = (const float*)d_in[11];
    const float* er2b2 = (const float*)d_in[12];
    const float* emb   = (const float*)d_in[13];
    const float* dr1w1 = (const float*)d_in[14];
    const float* dr1b1 = (const float*)d_in[15];
    const float* dr1w2 = (const float*)d_in[16];
    const float* dr1b2 = (const float*)d_in[17];
    const float* dr2w1 = (const float*)d_in[18];
    const float* dr2b1 = (const float*)d_in[19];
    const float* dr2w2 = (const float*)d_in[20];
    const float* dr2b2 = (const float*)d_in[21];
    const float* dt1w  = (const float*)d_in[22];
    const float* dt1b  = (const float*)d_in[23];
    const float* dt2w  = (const float*)d_in[24];
    const float* dt2b  = (const float*)d_in[25];

    float* outp = (float*)d_out;
    float* xt = outp;                    // x_tilde 1,572,864
    float* ze = outp + 1572864;          // z_e_x   8,388,608
    float* zq = ze + 8388608;            // z_q_x   8,388,608

    char* ws = (char*)d_ws;
    unsigned short* h1B  = (unsigned short*)(ws);                 // 67,108,864 B
    unsigned short* B0   = (unsigned short*)(ws + 67108864);      // 16,777,216
    unsigned short* B1   = (unsigned short*)(ws + 83886080);      // 16,777,216
    unsigned short* T3   = (unsigned short*)(ws + 100663296);     // 16,777,216
    float*          F0   = (float*)(ws + 117440512);              // 33,554,432
    float*          F1   = (float*)(ws + 150994944);              // 33,554,432
    unsigned short* WtC2 = (unsigned short*)(ws + 184549376);     // 2,097,152
    unsigned short* Wt31 = (unsigned short*)(ws + 186646528);     // 1,179,648
    unsigned short* Wt32 = (unsigned short*)(ws + 187826176);
    unsigned short* Wt33 = (unsigned short*)(ws + 189005824);
    unsigned short* Wt34 = (unsigned short*)(ws + 190185472);
    unsigned short* W11  = (unsigned short*)(ws + 191365120);     // 131,072
    unsigned short* W12  = (unsigned short*)(ws + 191496192);
    unsigned short* W13  = (unsigned short*)(ws + 191627264);
    unsigned short* W14  = (unsigned short*)(ws + 191758336);
    unsigned short* WtT1 = (unsigned short*)(ws + 191889408);     // 2,097,152
    unsigned short* WtT2 = (unsigned short*)(ws + 193986560);     // 24,576
    float*          e2v  = (float*)(ws + 194011136);              // 2,048
    int*            lat  = (int*)(ws + 194013184);                // 131,072
    unsigned short* embB = (unsigned short*)(ws + 194144256);     // 262,144
    float*          zpad = (float*)(ws + 194406400);              // 1,024 (zeros)

    // weight transforms + e2 + zero-page + emb cast
    k_e2<<<3, 256, 0, stream>>>(emb, e2v, zpad);
    k_embcast<<<512, 256, 0, stream>>>(emb, embB);
    k_wt16<<<256, 256, 0, stream>>>(ec2w, WtC2, 4096, 16);
    k_wt16<<<256, 256, 0, stream>>>(dt1w, WtT1, 16, 4096);
    k_wt3<<<dim3(256, 4), 256, 0, stream>>>(er1w1, er2w1, dr1w1, dr2w1,
                                            Wt31, Wt32, Wt33, Wt34);
    k_wt1<<<dim3(256, 4), 256, 0, stream>>>(er1w2, er2w2, dr1w2, dr2w2,
                                            W11, W12, W13, W14);
    k_wt<<<48, 256, 0, stream>>>(dt2w, WtT2, 12288, 3, 256, 16, 48);

    const unsigned short* zp16 = (const unsigned short*)zpad;
    // encoder
    k_conv1<<<dim3(16, 32, 4), 256, 0, stream>>>(x, ec1w, ec1b, h1B);
    k_cgemm<0,true,false><<<dim3(2,8,32), 256, 0, stream>>>(h1B, WtC2, ec2b,
            nullptr, zp16, B0, F0, nullptr);
    k_cgemm<1,true,false><<<dim3(2,8,32), 256, 0, stream>>>(B0, Wt31, er1b1,
            nullptr, zp16, T3, nullptr, nullptr);
    k_cgemm<2,false,true><<<dim3(2,8,32), 256, 0, stream>>>(T3, W11, er1b2,
            F0, zp16, B1, F1, nullptr);
    k_cgemm<1,true,false><<<dim3(2,8,32), 256, 0, stream>>>(B1, Wt32, er2b1,
            nullptr, zp16, T3, nullptr, nullptr);
    k_cgemm<2,false,false><<<dim3(2,8,32), 256, 0, stream>>>(T3, W12, er2b2,
            F1, zp16, B0, nullptr, ze);
    // VQ (MFMA) + gather
    k_vqm<<<512, 256, 0, stream>>>(B0, embB, e2v, lat);
    k_gather<<<dim3(32,32), 256, 0, stream>>>(lat, emb, zq, B0, F0);
    // decoder
    k_cgemm<1,true,false><<<dim3(2,8,32), 256, 0, stream>>>(B0, Wt33, dr1b1,
            nullptr, zp16, T3, nullptr, nullptr);
    k_cgemm<2,false,true><<<dim3(2,8,32), 256, 0, stream>>>(T3, W13, dr1b2,
            F0, zp16, B1, F1, nullptr);
    k_cgemm<1,true,false><<<dim3(2,8,32), 256, 0, stream>>>(B1, Wt34, dr2b1,
            nullptr, zp16, T3, nullptr, nullptr);
    k_cgemm<2,false,false><<<dim3(2,8,32), 256, 0, stream>>>(T3, W14, dr2b2,
            F1, zp16, B0, nullptr, nullptr);
    k_cgemm<3,true,false><<<dim3(2,8,128), 256, 0, stream>>>(B0, WtT1, dt1b,
            nullptr, zp16, h1B, nullptr, nullptr);
    k_convt2<<<dim3(32,32), 256, 0, stream>>>(h1B, WtT2, dt2b, xt);
}

// Round 9
// 964.579 us; speedup vs baseline: 2.1196x; 1.0381x over previous
//
#include <hip/hip_runtime.h>
#include <math.h>

using frag_ab = __attribute__((ext_vector_type(8))) short;
using f32x4   = __attribute__((ext_vector_type(4))) float;

__device__ __forceinline__ unsigned short f2b(float f) {
    unsigned u = __float_as_uint(f);
    u += 0x7fffu + ((u >> 16) & 1u);       // RNE
    return (unsigned short)(u >> 16);
}
__device__ __forceinline__ void bf8_to_f(uint4 v, float* f) {
    const unsigned* p = (const unsigned*)&v;
    #pragma unroll
    for (int q = 0; q < 4; ++q) {
        unsigned u = p[q];
        f[2*q]   = __uint_as_float(u << 16);
        f[2*q+1] = __uint_as_float(u & 0xffff0000u);
    }
}
// async 16B global->LDS (dest must be wave-uniform-base + lane*16 linear)
__device__ __forceinline__ void gload16(const void* g, void* l) {
    __builtin_amdgcn_global_load_lds(g, l, 16, 0, 0);
}

// ---------------- weight transforms: out[tap][co][ci] bf16 ------------------
__global__ void k_wt(const float* __restrict__ in, unsigned short* __restrict__ out,
                     int total, int CO, int CI, int sO, int sI) {
    int i = blockIdx.x * 256 + threadIdx.x;
    if (i >= total) return;
    int ci = i % CI;
    int r  = i / CI;
    int co = r % CO;
    int tp = r / CO;
    out[i] = f2b(in[(size_t)co * sO + (size_t)ci * sI + tp]);
}
__global__ void k_wt16(const float* __restrict__ in, unsigned short* __restrict__ out,
                       int sO, int sI) {
    int i = blockIdx.x * 256 + threadIdx.x;      // < 65536 : i = co*256+ci
    int ci = i & 255, co = i >> 8;
    const float* p = in + (size_t)co * sO + (size_t)ci * sI;
    #pragma unroll
    for (int tp = 0; tp < 16; ++tp)
        out[tp * 65536 + i] = f2b(p[tp]);
}
__global__ void k_wt3(const float* p0, const float* p1, const float* p2, const float* p3,
                      unsigned short* o0, unsigned short* o1, unsigned short* o2,
                      unsigned short* o3) {
    int z = blockIdx.y;
    const float* in = (z == 0) ? p0 : (z == 1) ? p1 : (z == 2) ? p2 : p3;
    unsigned short* out = (z == 0) ? o0 : (z == 1) ? o1 : (z == 2) ? o2 : o3;
    int i = blockIdx.x * 256 + threadIdx.x;      // < 65536
    int ci = i & 255, co = i >> 8;
    const float* p = in + (size_t)co * 2304 + (size_t)ci * 9;
    #pragma unroll
    for (int tp = 0; tp < 9; ++tp)
        out[tp * 65536 + i] = f2b(p[tp]);
}
__global__ void k_wt1(const float* p0, const float* p1, const float* p2, const float* p3,
                      unsigned short* o0, unsigned short* o1, unsigned short* o2,
                      unsigned short* o3) {
    int z = blockIdx.y;
    const float* in = (z == 0) ? p0 : (z == 1) ? p1 : (z == 2) ? p2 : p3;
    unsigned short* out = (z == 0) ? o0 : (z == 1) ? o1 : (z == 2) ? o2 : o3;
    int i = blockIdx.x * 256 + threadIdx.x;      // < 65536
    int ci = i & 255, co = i >> 8;
    out[i] = f2b(in[co * 256 + ci]);
}
__global__ void k_embcast(const float* __restrict__ in, unsigned short* __restrict__ out) {
    int i = blockIdx.x * 256 + threadIdx.x;
    out[i] = f2b(in[i]);
}

// e2[k] = sum_d emb[k][d]^2 ; block 2 zeroes the OOB zero-page
__global__ void k_e2(const float* __restrict__ emb, float* __restrict__ e2,
                     float* __restrict__ zpad) {
    if (blockIdx.x == 2) { zpad[threadIdx.x] = 0.f; return; }
    int k = blockIdx.x * 256 + threadIdx.x;
    if (k < 512) {
        const float* r = emb + k * 256;
        float s = 0.f;
        #pragma unroll 8
        for (int d = 0; d < 256; ++d) s += r[d] * r[d];
        e2[k] = s;
    }
}

// ---------------- conv1: 4x4 s2 p1, 3->256, 128->64, relu, NHWC bf16 out ----
__global__ __launch_bounds__(256) void k_conv1(const float* __restrict__ x,
        const float* __restrict__ w, const float* __restrict__ bias,
        unsigned short* __restrict__ out) {
    int t = threadIdx.x;
    int y = blockIdx.x * 4 + (t >> 6);
    int xq = t & 63;
    int b = blockIdx.y;
    int co0 = blockIdx.z * 64;
    float patch[48];
    #pragma unroll
    for (int ci = 0; ci < 3; ++ci)
        #pragma unroll
        for (int ky = 0; ky < 4; ++ky)
            #pragma unroll
            for (int kx = 0; kx < 4; ++kx) {
                int sy = 2*y - 1 + ky, sx = 2*xq - 1 + kx;
                float v = 0.f;
                if ((unsigned)sy < 128u && (unsigned)sx < 128u)
                    v = x[((b*3 + ci)*128 + sy)*128 + sx];
                patch[(ci*4 + ky)*4 + kx] = v;
            }
    unsigned short* op = out + (((size_t)(b*64 + y)*64 + xq) << 8) + co0;
    for (int c8 = 0; c8 < 8; ++c8) {
        unsigned short u8[8];
        #pragma unroll
        for (int cc = 0; cc < 8; ++cc) {
            int co = co0 + c8*8 + cc;
            float a = bias[co];
            #pragma unroll
            for (int k = 0; k < 48; ++k) a = fmaf(w[co*48 + k], patch[k], a);
            u8[cc] = f2b(fmaxf(a, 0.f));
        }
        *(uint4*)(op + c8*8) = *(uint4*)u8;
    }
}

// ---------------- unified implicit-GEMM conv (bf16 MFMA, 2-phase dbuf) ------
// block 256 = 4 waves; tile M=128 px x N=128 co; K in 64-ci chunks,
// double-buffered: stage(next) || MFMA(cur), one barrier per chunk.
template<int MODE, bool RELU_OUT, bool RELU_B16>
__global__ __launch_bounds__(256) void k_cgemm(
        const unsigned short* __restrict__ A,   // bf16 NHWC [B][Hin][Win][256]
        const unsigned short* __restrict__ Wt,  // bf16 [T][256co][256ci]
        const float* __restrict__ bias,
        const float* __restrict__ skipF,        // fp32 NHWC (nullable)
        const unsigned short* __restrict__ zpad,// >=16B zeros (OOB source)
        unsigned short* __restrict__ outB,      // bf16 NHWC (nullable)
        float* __restrict__ outFn,              // fp32 NHWC (nullable)
        float* __restrict__ outFc) {            // fp32 NCHW 32x32 (nullable)
    constexpr int NTAPS = (MODE==0) ? 16 : (MODE==1) ? 9 : (MODE==2) ? 1 : 4;
    constexpr int NCH   = NTAPS * 4;            // 64-ci chunks over all taps
    constexpr int HIN   = (MODE==0) ? 64 : 32;
    constexpr bool ISCT = (MODE==3);

    __shared__ __align__(16) unsigned short As[2][128*64];  // 16 KB each
    __shared__ __align__(16) unsigned short Bs[2][128*64];

    int t = threadIdx.x;
    int cob = blockIdx.x;            // 0..1 : co block of 128
    int y0  = blockIdx.y * 4;        // 4 out-rows in 32-grid
    int bz  = blockIdx.z;
    int b   = ISCT ? (bz >> 2) : bz;
    int par = ISCT ? (bz & 3) : 0;
    int psy = par >> 1, psx = par & 1;

    int srow = t >> 3;               // 0..31 (row within staging pass)
    int scc  = t & 7;                // 16B chunk within 128B row
    int sc2  = scc ^ (srow & 7);     // inverse-swizzled source chunk

    int wv = t >> 6, lane = t & 63;
    int mq = (wv >> 1) * 64, nq = (wv & 1) * 64;
    int lg = lane >> 4, lr = lane & 15;

    f32x4 acc[4][4];
    #pragma unroll
    for (int i = 0; i < 4; ++i)
        #pragma unroll
        for (int j = 0; j < 4; ++j) acc[i][j] = (f32x4){0.f,0.f,0.f,0.f};

    auto stage = [&](int n, int buf) {
        int tap = n >> 2, kk0 = (n & 3) * 64;
        int tdy, tdx, wtap;
        if (MODE == 0)      { tdy = tap >> 2; tdx = tap & 3; wtap = tap; }
        else if (MODE == 1) { tdy = tap / 3;  tdx = tap % 3; wtap = tap; }
        else if (MODE == 2) { tdy = 0; tdx = 0; wtap = 0; }
        else { int jy = tap >> 1, jx = tap & 1;
               tdy = psy - jy; tdx = psx - jx;
               wtap = ((psy ? 0 : 1) + 2*jy) * 4 + ((psx ? 0 : 1) + 2*jx); }
        const unsigned short* wb = Wt + ((size_t)wtap << 16) + ((size_t)cob << 15);
        #pragma unroll
        for (int q = 0; q < 4; ++q) {
            int row = srow + 32*q;
            int soy = y0 + (row >> 5), sox = row & 31;
            int sy = (MODE == 0) ? (2*soy - 1 + tdy)
                   : (MODE == 1) ? (soy - 1 + tdy) : (soy + tdy);
            int sx = (MODE == 0) ? (2*sox - 1 + tdx)
                   : (MODE == 1) ? (sox - 1 + tdx) : (sox + tdx);
            bool val = ((unsigned)sy < (unsigned)HIN) && ((unsigned)sx < (unsigned)HIN);
            const unsigned short* asrc = val
                ? A + ((((size_t)(b*HIN + sy))*HIN + sx) << 8) + kk0 + sc2*8
                : zpad;
            gload16(asrc, (char*)As[buf] + q*4096 + t*16);
            gload16(wb + (((size_t)row) << 8) + kk0 + sc2*8,
                    (char*)Bs[buf] + q*4096 + t*16);
        }
    };

    stage(0, 0);
    __syncthreads();
    for (int n = 0; n < NCH; ++n) {
        int cur = n & 1;
        if (n + 1 < NCH) stage(n + 1, cur ^ 1);
        #pragma unroll
        for (int ks = 0; ks < 2; ++ks) {
            int c = ks*4 + lg;                   // 0..7 : 8-elem group in 64 ci
            frag_ab af[4], bf[4];
            #pragma unroll
            for (int i = 0; i < 4; ++i) {
                int ar = mq + i*16 + lr;
                af[i] = *(const frag_ab*)((const char*)As[cur] + ar*128 + ((c ^ (ar & 7)) << 4));
                int br = nq + i*16 + lr;
                bf[i] = *(const frag_ab*)((const char*)Bs[cur] + br*128 + ((c ^ (br & 7)) << 4));
            }
            #pragma unroll
            for (int i = 0; i < 4; ++i)
                #pragma unroll
                for (int j = 0; j < 4; ++j)
                    acc[i][j] = __builtin_amdgcn_mfma_f32_16x16x32_bf16(
                                    af[i], bf[j], acc[i][j], 0, 0, 0);
        }
        __syncthreads();
    }

    #pragma unroll
    for (int mf = 0; mf < 4; ++mf) {
        #pragma unroll
        for (int nf = 0; nf < 4; ++nf) {
            int co = cob*128 + nq + nf*16 + lr;
            float bb = bias[co];
            f32x4 v = acc[mf][nf];
            #pragma unroll
            for (int j = 0; j < 4; ++j) {
                int prow = mq + mf*16 + lg*4 + j;
                int oy = y0 + (prow >> 5);
                int ox = prow & 31;
                size_t pix;
                if (ISCT) pix = ((size_t)(b*64 + (2*oy + psy)))*64 + (2*ox + psx);
                else      pix = ((size_t)(b*32 + oy))*32 + ox;
                float xv = v[j] + bb;
                if (skipF) xv += skipF[pix*256 + co];
                if (RELU_OUT) xv = fmaxf(xv, 0.f);
                if (outB)  outB[pix*256 + co] = f2b(RELU_B16 ? fmaxf(xv, 0.f) : xv);
                if (outFn) outFn[pix*256 + co] = xv;
                if (outFc) outFc[(((size_t)b*256 + co) << 10) + oy*32 + ox] = xv;
            }
        }
    }
}

// ---------------- VQ via MFMA: dots = Z_bf16 @ E_bf16^T, argmin epilogue ----
__global__ __launch_bounds__(256) void k_vqm(const unsigned short* __restrict__ zB,
        const unsigned short* __restrict__ eB,   // [512][256] bf16
        const float* __restrict__ e2, int* __restrict__ lat) {
    __shared__ __align__(16) unsigned short As[64*256];  // 32 KB, row=pos
    __shared__ __align__(16) unsigned short Bs[64*256];  // 32 KB, row=k-in-chunk
    int t = threadIdx.x;
    int pos0 = blockIdx.x * 64;
    #pragma unroll
    for (int q = 0; q < 8; ++q) {
        int idx = q*256 + t;
        int row = idx >> 5, ch = idx & 31;
        uint4 v = *(const uint4*)(zB + (((size_t)(pos0 + row)) << 8) + ch*8);
        *(uint4*)((char*)As + row*512 + ((ch ^ (row & 7)) << 4)) = v;
    }
    int wv = t >> 6, lane = t & 63;
    int lg = lane >> 4, lr = lane & 15;
    int arow = wv*16 + lr;
    int aswz[8];
    #pragma unroll
    for (int kk = 0; kk < 8; ++kk)
        aswz[kk] = arow*512 + (((kk*4 + lg) ^ (arow & 7)) << 4);
    float minv[4] = {1e30f, 1e30f, 1e30f, 1e30f};
    int   mink[4] = {0, 0, 0, 0};
    for (int kc = 0; kc < 8; ++kc) {
        __syncthreads();
        #pragma unroll
        for (int q = 0; q < 8; ++q) {
            int idx = q*256 + t;
            int row = idx >> 5, ch = idx & 31;
            uint4 v = *(const uint4*)(eB + (((size_t)(kc*64 + row)) << 8) + ch*8);
            *(uint4*)((char*)Bs + row*512 + ((ch ^ (row & 7)) << 4)) = v;
        }
        __syncthreads();
        #pragma unroll
        for (int nt = 0; nt < 4; ++nt) {
            int brow = nt*16 + lr;
            f32x4 acc = (f32x4){0.f, 0.f, 0.f, 0.f};
            #pragma unroll
            for (int kk = 0; kk < 8; ++kk) {
                frag_ab a = *(const frag_ab*)((const char*)As + aswz[kk]);
                frag_ab b = *(const frag_ab*)((const char*)Bs
                              + brow*512 + (((kk*4 + lg) ^ (brow & 7)) << 4));
                acc = __builtin_amdgcn_mfma_f32_16x16x32_bf16(a, b, acc, 0, 0, 0);
            }
            int k = kc*64 + nt*16 + lr;
            float ee = e2[k];
            #pragma unroll
            for (int j = 0; j < 4; ++j) {
                float dist = ee - 2.f * acc[j];
                if (dist < minv[j]) { minv[j] = dist; mink[j] = k; }
            }
        }
    }
    #pragma unroll
    for (int s = 1; s < 16; s <<= 1) {
        #pragma unroll
        for (int j = 0; j < 4; ++j) {
            float ov = __shfl_xor(minv[j], s, 64);
            int   ok = __shfl_xor(mink[j], s, 64);
            if (ov < minv[j] || (ov == minv[j] && ok < mink[j])) {
                minv[j] = ov; mink[j] = ok;
            }
        }
    }
    if (lr == 0) {
        #pragma unroll
        for (int j = 0; j < 4; ++j)
            lat[pos0 + wv*16 + lg*4 + j] = mink[j];
    }
}

// gather: zq NCHW fp32 (d_out, raw) + NHWC bf16 (RELU'd) + NHWC fp32 (raw skip)
__global__ __launch_bounds__(256) void k_gather(const int* __restrict__ lat,
        const float* __restrict__ emb, float* __restrict__ zqc,
        unsigned short* __restrict__ zqB, float* __restrict__ zqF) {
    __shared__ int ll[32];
    int t = threadIdx.x, y = blockIdx.x, b = blockIdx.y;
    if (t < 32) ll[t] = lat[(b * 32 + y) * 32 + t];
    __syncthreads();
    #pragma unroll
    for (int i = 0; i < 32; ++i) {
        int l = i * 256 + t;
        int d = l >> 5, xx = l & 31;
        zqc[(((size_t)b*256 + d) << 10) + y*32 + xx] = emb[ll[xx]*256 + d];
    }
    int xx = t & 31, dg = t >> 5;
    const float* e = emb + ll[xx]*256 + dg*32;
    size_t off = ((((size_t)(b*32 + y)*32 + xx)) << 8) + dg*32;
    #pragma unroll
    for (int q = 0; q < 8; ++q) {
        float4 v = *(const float4*)(e + q*4);
        *(float4*)(zqF + off + q*4) = v;
        uint2 pk;
        pk.x = (unsigned)f2b(fmaxf(v.x, 0.f)) | ((unsigned)f2b(fmaxf(v.y, 0.f)) << 16);
        pk.y = (unsigned)f2b(fmaxf(v.z, 0.f)) | ((unsigned)f2b(fmaxf(v.w, 0.f)) << 16);
        *(uint2*)(zqB + off + q*4) = pk;
    }
}

// ---------------- convT2: 4x4 s2 p1, 256->3, 64->128, sigmoid, NCHW fp32 ----
// slab row stride 40 shorts (80 B): breaks the 64B-stride bank pattern.
__global__ __launch_bounds__(256) void k_convt2(const unsigned short* __restrict__ in,
        const unsigned short* __restrict__ Wt,  // [16][3][256] bf16
        const float* __restrict__ bias, float* __restrict__ out) {
    __shared__ __align__(16) unsigned short slab[4*66*40];
    __shared__ __align__(16) unsigned short wl[16*3*32];
    int t = threadIdx.x;
    int b = blockIdx.y;
    int oy0 = blockIdx.x * 4;
    int u0 = oy0 >> 1;
    int oyl = t >> 7, ox = t & 127;
    int sy = oyl & 1, sx = ox & 1;
    int v = ox >> 1;
    float acc0[3] = {0.f,0.f,0.f}, acc1[3] = {0.f,0.f,0.f};
    for (int kc = 0; kc < 8; ++kc) {
        __syncthreads();
        for (int i = t; i < 4*66*4; i += 256) {
            int g = i & 3; int cidx = i >> 2;
            int cc = cidx % 66, ri = cidx / 66;
            int iy = u0 - 1 + ri, ix = cc - 1;
            uint4 v4 = {0,0,0,0};
            if ((unsigned)iy < 64u && (unsigned)ix < 64u)
                v4 = *(const uint4*)(in + (((size_t)(b*64 + iy)*64 + ix) << 8)
                                        + kc*32 + g*8);
            *(uint4*)(&slab[(ri*66 + cc)*40 + g*8]) = v4;
        }
        for (int i = t; i < 1536; i += 256)
            wl[i] = Wt[(i >> 5) * 256 + kc*32 + (i & 31)];
        __syncthreads();
        #pragma unroll
        for (int jy = 0; jy < 2; ++jy) {
            int duy = sy - jy;
            int riA = 1 + duy;
            #pragma unroll
            for (int jx = 0; jx < 2; ++jx) {
                int dvx = sx - jx;
                int cc = v + dvx + 1;
                int wtap = ((sy ? 0 : 1) + 2*jy)*4 + ((sx ? 0 : 1) + 2*jx);
                const unsigned short* sA = &slab[(riA*66 + cc)*40];
                const unsigned short* sB = sA + 66*40;
                const unsigned short* wp = &wl[wtap*96];
                #pragma unroll
                for (int c8 = 0; c8 < 4; ++c8) {
                    float fA[8], fB[8], w0[8], w1[8], w2[8];
                    bf8_to_f(*(const uint4*)(sA + c8*8), fA);
                    bf8_to_f(*(const uint4*)(sB + c8*8), fB);
                    bf8_to_f(*(const uint4*)(wp + c8*8), w0);
                    bf8_to_f(*(const uint4*)(wp + 32 + c8*8), w1);
                    bf8_to_f(*(const uint4*)(wp + 64 + c8*8), w2);
                    #pragma unroll
                    for (int q = 0; q < 8; ++q) {
                        acc0[0] = fmaf(fA[q], w0[q], acc0[0]);
                        acc0[1] = fmaf(fA[q], w1[q], acc0[1]);
                        acc0[2] = fmaf(fA[q], w2[q], acc0[2]);
                        acc1[0] = fmaf(fB[q], w0[q], acc1[0]);
                        acc1[1] = fmaf(fB[q], w1[q], acc1[1]);
                        acc1[2] = fmaf(fB[q], w2[q], acc1[2]);
                    }
                }
            }
        }
    }
    #pragma unroll
    for (int co = 0; co < 3; ++co) {
        float b0 = acc0[co] + bias[co];
        float b1 = acc1[co] + bias[co];
        out[(((size_t)b*3 + co) << 14) + (oy0 + oyl)*128 + ox]     = 1.f/(1.f + __expf(-b0));
        out[(((size_t)b*3 + co) << 14) + (oy0 + oyl + 2)*128 + ox] = 1.f/(1.f + __expf(-b1));
    }
}

extern "C" void kernel_launch(void* const* d_in, const int* in_sizes, int n_in,
                              void* d_out, int out_size, void* d_ws, size_t ws_size,
                              hipStream_t stream) {
    const float* x     = (const float*)d_in[0];
    const float* ec1w  = (const float*)d_in[1];
    const float* ec1b  = (const float*)d_in[2];
    const float* ec2w  = (const float*)d_in[3];
    const float* ec2b  = (const float*)d_in[4];
    const float* er1w1 = (const float*)d_in[5];
    const float* er1b1 = (const float*)d_in[6];
    const float* er1w2 = (const float*)d_in[7];
    const float* er1b2 = (const float*)d_in[8];
    const float* er2w1 = (const float*)d_in[9];
    const float* er2b1 = (const float*)d_in[10];
    const float* er2w2 = (const float*)d_in[11];
    const float* er2b2 = (const float*)d_in[12];
    const float* emb   = (const float*)d_in[13];
    const float* dr1w1 = (const float*)d_in[14];
    const float* dr1b1 = (const float*)d_in[15];
    const float* dr1w2 = (const float*)d_in[16];
    const float* dr1b2 = (const float*)d_in[17];
    const float* dr2w1 = (const float*)d_in[18];
    const float* dr2b1 = (const float*)d_in[19];
    const float* dr2w2 = (const float*)d_in[20];
    const float* dr2b2 = (const float*)d_in[21];
    const float* dt1w  = (const float*)d_in[22];
    const float* dt1b  = (const float*)d_in[23];
    const float* dt2w  = (const float*)d_in[24];
    const float* dt2b  = (const float*)d_in[25];

    float* outp = (float*)d_out;
    float* xt = outp;                    // x_tilde 1,572,864
    float* ze = outp + 1572864;          // z_e_x   8,388,608
    float* zq = ze + 8388608;            // z_q_x   8,388,608

    char* ws = (char*)d_ws;
    unsigned short* h1B  = (unsigned short*)(ws);                 // 67,108,864 B
    unsigned short* B0   = (unsigned short*)(ws + 67108864);      // 16,777,216
    unsigned short* B1   = (unsigned short*)(ws + 83886080);      // 16,777,216
    unsigned short* T3   = (unsigned short*)(ws + 100663296);     // 16,777,216
    float*          F0   = (float*)(ws + 117440512);              // 33,554,432
    float*          F1   = (float*)(ws + 150994944);              // 33,554,432
    unsigned short* WtC2 = (unsigned short*)(ws + 184549376);     // 2,097,152
    unsigned short* Wt31 = (unsigned short*)(ws + 186646528);     // 1,179,648
    unsigned short* Wt32 = (unsigned short*)(ws + 187826176);
    unsigned short* Wt33 = (unsigned short*)(ws + 189005824);
    unsigned short* Wt34 = (unsigned short*)(ws + 190185472);
    unsigned short* W11  = (unsigned short*)(ws + 191365120);     // 131,072
    unsigned short* W12  = (unsigned short*)(ws + 191496192);
    unsigned short* W13  = (unsigned short*)(ws + 191627264);
    unsigned short* W14  = (unsigned short*)(ws + 191758336);
    unsigned short* WtT1 = (unsigned short*)(ws + 191889408);     // 2,097,152
    unsigned short* WtT2 = (unsigned short*)(ws + 193986560);     // 24,576
    float*          e2v  = (float*)(ws + 194011136);              // 2,048
    int*            lat  = (int*)(ws + 194013184);                // 131,072
    unsigned short* embB = (unsigned short*)(ws + 194144256);     // 262,144
    float*          zpad = (float*)(ws + 194406400);              // 1,024 (zeros)

    // weight transforms + e2 + zero-page + emb cast
    k_e2<<<3, 256, 0, stream>>>(emb, e2v, zpad);
    k_embcast<<<512, 256, 0, stream>>>(emb, embB);
    k_wt16<<<256, 256, 0, stream>>>(ec2w, WtC2, 4096, 16);
    k_wt16<<<256, 256, 0, stream>>>(dt1w, WtT1, 16, 4096);
    k_wt3<<<dim3(256, 4), 256, 0, stream>>>(er1w1, er2w1, dr1w1, dr2w1,
                                            Wt31, Wt32, Wt33, Wt34);
    k_wt1<<<dim3(256, 4), 256, 0, stream>>>(er1w2, er2w2, dr1w2, dr2w2,
                                            W11, W12, W13, W14);
    k_wt<<<48, 256, 0, stream>>>(dt2w, WtT2, 12288, 3, 256, 16, 48);

    const unsigned short* zp16 = (const unsigned short*)zpad;
    // encoder
    k_conv1<<<dim3(16, 32, 4), 256, 0, stream>>>(x, ec1w, ec1b, h1B);
    k_cgemm<0,true,false><<<dim3(2,8,32), 256, 0, stream>>>(h1B, WtC2, ec2b,
            nullptr, zp16, B0, F0, nullptr);
    k_cgemm<1,true,false><<<dim3(2,8,32), 256, 0, stream>>>(B0, Wt31, er1b1,
            nullptr, zp16, T3, nullptr, nullptr);
    k_cgemm<2,false,true><<<dim3(2,8,32), 256, 0, stream>>>(T3, W11, er1b2,
            F0, zp16, B1, F1, nullptr);
    k_cgemm<1,true,false><<<dim3(2,8,32), 256, 0, stream>>>(B1, Wt32, er2b1,
            nullptr, zp16, T3, nullptr, nullptr);
    k_cgemm<2,false,false><<<dim3(2,8,32), 256, 0, stream>>>(T3, W12, er2b2,
            F1, zp16, B0, nullptr, ze);
    // VQ (MFMA) + gather
    k_vqm<<<512, 256, 0, stream>>>(B0, embB, e2v, lat);
    k_gather<<<dim3(32,32), 256, 0, stream>>>(lat, emb, zq, B0, F0);
    // decoder
    k_cgemm<1,true,false><<<dim3(2,8,32), 256, 0, stream>>>(B0, Wt33, dr1b1,
            nullptr, zp16, T3, nullptr, nullptr);
    k_cgemm<2,false,true><<<dim3(2,8,32), 256, 0, stream>>>(T3, W13, dr1b2,
            F0, zp16, B1, F1, nullptr);
    k_cgemm<1,true,false><<<dim3(2,8,32), 256, 0, stream>>>(B1, Wt34, dr2b1,
            nullptr, zp16, T3, nullptr, nullptr);
    k_cgemm<2,false,false><<<dim3(2,8,32), 256, 0, stream>>>(T3, W14, dr2b2,
            F1, zp16, B0, nullptr, nullptr);
    k_cgemm<3,true,false><<<dim3(2,8,128), 256, 0, stream>>>(B0, WtT1, dt1b,
            nullptr, zp16, h1B, nullptr, nullptr);
    k_convt2<<<dim3(32,32), 256, 0, stream>>>(h1B, WtT2, dt2b, xt);
}